// Round 1
// baseline (2525.726 us; speedup 1.0000x reference)
//
#include <hip/hip_runtime.h>
#include <hip/hip_bf16.h>

typedef unsigned short u16;
typedef __attribute__((ext_vector_type(8))) short short8;
typedef __attribute__((ext_vector_type(4))) float floatx4;

__device__ __forceinline__ u16 f2bf(float f) {
    union { float f; unsigned u; } v; v.f = f;
    unsigned r = v.u + 0x7FFF + ((v.u >> 16) & 1);
    return (u16)(r >> 16);
}
__device__ __forceinline__ float bf2f(u16 h) {
    union { unsigned u; float f; } v; v.u = ((unsigned)h) << 16;
    return v.f;
}

// ---------------------------------------------------------------------------
// Wstack fragment builder: Wf[gk][ntile][lane][8] bf16, K = 13*512 = 6656.
// rows k<6144: W[r][h][n] = sum_q comb[r,q] basis[q,h,n]  (r=k>>9, h=k&511)
// rows k>=6144: self^T: self[n][k-6144]
__global__ void k_wstack(const float* __restrict__ basis, const float* __restrict__ comb,
                         const float* __restrict__ selfW, u16* __restrict__ wf) {
    int tid = blockIdx.x * 256 + threadIdx.x;   // < 208*32*64
    if (tid >= 208 * 32 * 64) return;
    int lane = tid & 63;
    int n = ((tid >> 6) & 31) * 16 + (lane & 15);
    int k0 = (tid >> 11) * 32 + ((lane >> 4) << 3);
    short8 ov;
    for (int j = 0; j < 8; ++j) {
        int k = k0 + j;
        float v;
        if (k < 6144) {
            int r = k >> 9, h = k & 511;
            v = 0.f;
            for (int q = 0; q < 6; ++q)
                v += comb[r * 6 + q] * basis[(q * 512 + h) * 512 + n];
        } else {
            v = selfW[n * 512 + (k - 6144)];
        }
        ov[j] = (short)f2bf(v);
    }
    *(((short8*)wf) + tid) = ov;
}

// ---------------------------------------------------------------------------
// Adjacency prep: adjA[b][r][64][64] = raw ch r+1 (rgcn1);
// adjB = update_adjacency(parity OR on ch 11/12 at S=64, drop idx 62) remapped.
__global__ void k_adj(const int* __restrict__ A, u16* __restrict__ adjA, u16* __restrict__ adjB) {
    int bi = blockIdx.x;          // b*12 + r
    int b = bi / 12, r = bi % 12;
    const int* Ab = A + (size_t)(b * 13 + (r + 1)) * 62 * 62;
    u16* oA = adjA + (size_t)bi * 64 * 64;
    u16* oB = adjB + (size_t)bi * 64 * 64;
    int t = threadIdx.x;
    int n = t >> 2, m0 = (t & 3) * 16;
    for (int i = 0; i < 16; ++i) {
        int m = m0 + i;
        u16 va = 0;
        if (n < 62 && m < 62) va = Ab[n * 62 + m] ? 0x3F80 : 0;
        oA[n * 64 + m] = va;
        u16 vb = 0;
        if (n < 63 && m < 63) {
            int oi = (n == 62) ? 63 : n, oj = (m == 62) ? 63 : m;
            int val = 0;
            if (oi < 62 && oj < 62) val = Ab[oi * 62 + oj] ? 1 : 0;
            int lo = (oi < oj) ? oi : oj, hi = (oi < oj) ? oj : oi;
            if (hi == lo + 2) {
                int p = (lo >> 1) & 1;
                int chp = ((lo & 1) == 0) ? (p ? 12 : 11) : (p ? 11 : 12);
                if (r + 1 == chp) val = 1;
            }
            vb = val ? 0x3F80 : 0;
        }
        oB[n * 64 + m] = vb;
    }
}

// ---------------------------------------------------------------------------
// initial node embedding -> mi1 rows 60,61; mi2 row 62; zero pad rows.
__global__ void k_prep(const int* __restrict__ player,
                       const float* __restrict__ pAx, const float* __restrict__ pAy,
                       const float* __restrict__ pBx, const float* __restrict__ pBy,
                       const float* __restrict__ emb, const float* __restrict__ cW,
                       const float* __restrict__ cb, const float* __restrict__ inW,
                       const float* __restrict__ inb,
                       u16* __restrict__ mi1, u16* __restrict__ mi2) {
    int b = blockIdx.x, t = threadIdx.x;
    __shared__ float feat[2][64];
    if (t < 64) {
        int j = t >> 5, d = t & 31;
        float X = j ? pBx[b] : pAx[b];
        float Y = j ? pBy[b] : pAy[b];
        feat[j][d] = fmaxf(cW[d * 2] * X + cW[d * 2 + 1] * Y + cb[d], 0.f);
        feat[j][32 + d] = emb[player[b * 2 + j] * 32 + d];
    }
    __syncthreads();
    for (int h = t; h < 512; h += 256) {
        float a0 = inb[h], a1 = inb[h];
        const float* wrow = inW + h * 64;
        #pragma unroll
        for (int d = 0; d < 64; ++d) {
            float wv = wrow[d];
            a0 += wv * feat[0][d];
            a1 += wv * feat[1][d];
        }
        u16 v0 = f2bf(a0), v1 = f2bf(a1);
        size_t base = (size_t)b * 64 * 512;
        mi1[base + 60 * 512 + h] = v0;
        mi1[base + 61 * 512 + h] = v1;
        mi2[base + 62 * 512 + h] = v1;
        mi1[base + 62 * 512 + h] = 0;
        mi1[base + 63 * 512 + h] = 0;
        mi2[base + 63 * 512 + h] = 0;
    }
}

// enc f32 -> mi1 rows 0..59, mi2 rows 0..57 (bf16)
__global__ void k_cast(const float* __restrict__ enc, u16* __restrict__ mi1, u16* __restrict__ mi2) {
    long long idx = (long long)blockIdx.x * 256 + threadIdx.x;
    long long e = idx * 8;
    if (e >= 256LL * 60 * 512) return;
    int b = (int)(e / (60 * 512));
    int rm = (int)(e % (60 * 512));
    int n = rm / 512, h = rm % 512;
    for (int i = 0; i < 8; ++i) {
        u16 v = f2bf(enc[e + i]);
        mi1[((size_t)b * 64 + n) * 512 + h + i] = v;
        if (n < 58) mi2[((size_t)b * 64 + n) * 512 + h + i] = v;
    }
}

// (B,64,512) -> (B,512,64) transpose via LDS
__global__ void k_transpose(const u16* __restrict__ in, u16* __restrict__ out) {
    int b = blockIdx.x >> 1, half = blockIdx.x & 1;
    __shared__ u16 tile[64][264];
    int t = threadIdx.x;
    int m = t >> 2, c0 = (t & 3) * 64;
    const u16* ip = in + ((size_t)b * 64 + m) * 512 + half * 256 + c0;
    for (int i = 0; i < 64; i += 8)
        *(short8*)&tile[m][c0 + i] = *(const short8*)(ip + i);
    __syncthreads();
    int h = t;
    u16* op = out + ((size_t)b * 512 + half * 256 + h) * 64;
    for (int mm = 0; mm < 64; mm += 8) {
        short8 ov;
        #pragma unroll
        for (int i = 0; i < 8; ++i) ov[i] = (short)tile[mm + i][h];
        *(short8*)(op + mm) = ov;
    }
}

// ---------------------------------------------------------------------------
// Layer-0 RGCN: one block per batch. y = relu([msg_r..., x] @ Wstack), 64x512.
__global__ __launch_bounds__(512, 2)
void k_gemm0(const u16* __restrict__ x,   // (B,64,512) bf16
             const u16* __restrict__ xT,  // (B,512,64) bf16
             const u16* __restrict__ adj, // (B,12,64,64) bf16
             const u16* __restrict__ wf,  // fragment-ordered Wstack
             u16* __restrict__ out) {
    int b = blockIdx.x;
    int t = threadIdx.x, lane = t & 63, w = t >> 6;
    int wr = w & 3, wc = w >> 2;
    int l15 = lane & 15, lq = lane >> 4;
    __shared__ u16 adjs[64 * 72];    // pitch 72
    __shared__ u16 xst[128 * 88];    // xst[h][m], pitch 88
    __shared__ u16 msgs[64 * 136];   // pitch 136
    floatx4 acc[16];
    #pragma unroll
    for (int i = 0; i < 16; ++i) acc[i] = (floatx4)(0.f);

    const u16* xb   = x  + (size_t)b * 64 * 512;
    const u16* xTb  = xT + (size_t)b * 512 * 64;
    const u16* adjb = adj + (size_t)b * 12 * 64 * 64;

    for (int hs = 0; hs < 4; ++hs) {
        __syncthreads();
        {   // stage xst[h][m] = xT[hs*128+h][m]
            int hh = t >> 2, m0 = (t & 3) * 16;
            const u16* p = xTb + (hs * 128 + hh) * 64 + m0;
            *(short8*)&xst[hh * 88 + m0]     = *(const short8*)p;
            *(short8*)&xst[hh * 88 + m0 + 8] = *(const short8*)(p + 8);
        }
        for (int kb = 0; kb < 13; ++kb) {
            if (kb < 12) {
                {   // stage adj_r
                    int n = t >> 3, m0 = (t & 7) * 8;
                    *(short8*)&adjs[n * 72 + m0] = *(const short8*)(adjb + (kb * 64 + n) * 64 + m0);
                }
                __syncthreads();
                // phase1: msgs = adj_r @ x_sub  (64 x 128)
                floatx4 mc[4];
                #pragma unroll
                for (int i = 0; i < 4; ++i) mc[i] = (floatx4)(0.f);
                for (int k0 = 0; k0 < 64; k0 += 32) {
                    short8 af = *(const short8*)&adjs[(wr * 16 + l15) * 72 + k0 + lq * 8];
                    #pragma unroll
                    for (int i = 0; i < 4; ++i) {
                        short8 bfg = *(const short8*)&xst[(wc * 64 + i * 16 + l15) * 88 + k0 + lq * 8];
                        mc[i] = __builtin_amdgcn_mfma_f32_16x16x32_bf16(af, bfg, mc[i], 0, 0, 0);
                    }
                }
                #pragma unroll
                for (int i = 0; i < 4; ++i)
                    #pragma unroll
                    for (int r = 0; r < 4; ++r)
                        msgs[(wr * 16 + lq * 4 + r) * 136 + wc * 64 + i * 16 + l15] = f2bf(mc[i][r]);
                __syncthreads();
            } else {
                __syncthreads();
                {   // self block: msgs = x_sub (row-major)
                    int n = t >> 3, c0 = (t & 7) * 16;
                    const u16* p = xb + n * 512 + hs * 128 + c0;
                    *(short8*)&msgs[n * 136 + c0]     = *(const short8*)p;
                    *(short8*)&msgs[n * 136 + c0 + 8] = *(const short8*)(p + 8);
                }
                __syncthreads();
            }
            // phase2: acc += msgs @ W[kb-block, hs-sub]
            #pragma unroll
            for (int ks = 0; ks < 4; ++ks) {
                int gk = kb * 16 + hs * 4 + ks;
                short8 af = *(const short8*)&msgs[(wr * 16 + l15) * 136 + ks * 32 + lq * 8];
                const u16* wp = wf + ((size_t)(gk * 32 + wc * 16) * 64 + lane) * 8;
                #pragma unroll
                for (int nt = 0; nt < 16; ++nt) {
                    short8 bfg = *(const short8*)(wp + (size_t)nt * 512);
                    acc[nt] = __builtin_amdgcn_mfma_f32_16x16x32_bf16(af, bfg, acc[nt], 0, 0, 0);
                }
            }
        }
    }
    u16* ob = out + (size_t)b * 64 * 512;
    #pragma unroll
    for (int nt = 0; nt < 16; ++nt)
        #pragma unroll
        for (int r = 0; r < 4; ++r) {
            int row = wr * 16 + lq * 4 + r;
            int col = wc * 256 + nt * 16 + l15;
            ob[row * 512 + col] = f2bf(fmaxf(acc[nt][r], 0.f));
        }
}

// ---------------------------------------------------------------------------
// Layer-1 msg rows: A[b*nout+ni][k] = [msg_r(node)..., x(node)]
__global__ void k_msgL1(const u16* __restrict__ x1, const u16* __restrict__ adj,
                        u16* __restrict__ Aout, int nout, int n0, int n1, int n2, int n3) {
    int bi = blockIdx.x;
    int b = bi / nout, ni = bi % nout;
    int nds[4] = {n0, n1, n2, n3};
    int n = nds[ni];
    int t = threadIdx.x;
    __shared__ u16 adjrow[12 * 64];
    const u16* ab = adj + (size_t)b * 12 * 64 * 64 + n * 64;
    for (int i = t; i < 768; i += 256) adjrow[i] = ab[(i >> 6) * 4096 + (i & 63)];
    __syncthreads();
    float s0[12], s1[12];
    #pragma unroll
    for (int r = 0; r < 12; ++r) { s0[r] = 0.f; s1[r] = 0.f; }
    const u16* xb = x1 + (size_t)b * 64 * 512;
    for (int m = 0; m < 64; ++m) {
        float xv0 = bf2f(xb[m * 512 + t]);
        float xv1 = bf2f(xb[m * 512 + t + 256]);
        #pragma unroll
        for (int r = 0; r < 12; ++r) {
            float av = bf2f(adjrow[r * 64 + m]);
            s0[r] += av * xv0;
            s1[r] += av * xv1;
        }
    }
    u16* Ar = Aout + (size_t)bi * 6656;
    #pragma unroll
    for (int r = 0; r < 12; ++r) {
        Ar[r * 512 + t]       = f2bf(s0[r]);
        Ar[r * 512 + t + 256] = f2bf(s1[r]);
    }
    Ar[6144 + t]       = xb[n * 512 + t];
    Ar[6144 + t + 256] = xb[n * 512 + t + 256];
}

// Layer-1 GEMM: sigmoid(A @ Wstack1). mode 0 -> mi2 rows 58..61 bf16; mode 1 -> t2 f32.
__global__ __launch_bounds__(512, 2)
void k_gemmL1(const u16* __restrict__ A, const u16* __restrict__ wf,
              int mode, u16* __restrict__ mi2, float* __restrict__ t2) {
    int mb = blockIdx.x, ct = blockIdx.y;
    int t = threadIdx.x, lane = t & 63, w = t >> 6;
    int wr = w & 3, wc = w >> 2;
    int l15 = lane & 15, lq = lane >> 4;
    floatx4 acc[4];
    #pragma unroll
    for (int i = 0; i < 4; ++i) acc[i] = (floatx4)(0.f);
    const u16* Ar = A + (size_t)(mb * 64 + wr * 16 + l15) * 6656 + lq * 8;
    for (int gk = 0; gk < 208; ++gk) {
        short8 af = *(const short8*)(Ar + gk * 32);
        const u16* wp = wf + ((size_t)(gk * 32 + ct * 8 + wc * 4) * 64 + lane) * 8;
        #pragma unroll
        for (int i = 0; i < 4; ++i) {
            short8 bfg = *(const short8*)(wp + (size_t)i * 512);
            acc[i] = __builtin_amdgcn_mfma_f32_16x16x32_bf16(af, bfg, acc[i], 0, 0, 0);
        }
    }
    #pragma unroll
    for (int i = 0; i < 4; ++i)
        #pragma unroll
        for (int r = 0; r < 4; ++r) {
            int Mrow = mb * 64 + wr * 16 + lq * 4 + r;
            int col = ct * 128 + wc * 64 + i * 16 + l15;
            float v = 1.f / (1.f + __expf(-acc[i][r]));
            if (mode == 0) {
                int b = Mrow >> 2, nidx = Mrow & 3;
                mi2[((size_t)b * 64 + 58 + nidx) * 512 + col] = f2bf(v);
            } else {
                t2[(size_t)Mrow * 512 + col] = v;
            }
        }
}

// logits = [black|white] @ type_W^T + type_b
__global__ void k_final(const float* __restrict__ t2, const float* __restrict__ tW,
                        const float* __restrict__ tb, float* __restrict__ outp) {
    int b = blockIdx.x, l = threadIdx.x;   // 64 threads
    float a[11];
    #pragma unroll
    for (int j = 0; j < 11; ++j) a[j] = 0.f;
    for (int it = 0; it < 16; ++it) {
        int h = it * 64 + l;
        float c = (h < 512) ? t2[(b * 2 + 1) * 512 + h] : t2[(b * 2 + 0) * 512 + (h - 512)];
        #pragma unroll
        for (int j = 0; j < 11; ++j) a[j] += c * tW[j * 1024 + h];
    }
    #pragma unroll
    for (int j = 0; j < 11; ++j) {
        float v = a[j];
        for (int off = 32; off > 0; off >>= 1) v += __shfl_down(v, off, 64);
        if (l == 0) outp[b * 11 + j] = v + tb[j];
    }
}

// ---------------------------------------------------------------------------
extern "C" void kernel_launch(void* const* d_in, const int* in_sizes, int n_in,
                              void* d_out, int out_size, void* d_ws, size_t ws_size,
                              hipStream_t stream) {
    const int*   player = (const int*)d_in[0];
    const float* enc    = (const float*)d_in[2];
    const int*   adjm   = (const int*)d_in[3];
    const float* pAx    = (const float*)d_in[4];
    const float* pAy    = (const float*)d_in[5];
    const float* pBx    = (const float*)d_in[6];
    const float* pBy    = (const float*)d_in[7];
    const float* emb    = (const float*)d_in[8];
    const float* cW     = (const float*)d_in[9];
    const float* cb     = (const float*)d_in[10];
    const float* inW    = (const float*)d_in[11];
    const float* inb    = (const float*)d_in[12];
    const float* basis0 = (const float*)d_in[13];
    const float* comb0  = (const float*)d_in[14];
    const float* self0  = (const float*)d_in[15];
    const float* basis1 = (const float*)d_in[16];
    const float* comb1  = (const float*)d_in[17];
    const float* self1  = (const float*)d_in[18];
    const float* typeW  = (const float*)d_in[19];
    const float* typeb  = (const float*)d_in[20];

    char* ws = (char*)d_ws;
    size_t off = 0;
    auto alloc = [&](size_t bytes) -> void* {
        void* p = ws + off;
        off = (off + bytes + 255) & ~(size_t)255;
        return p;
    };
    u16* mi1  = (u16*)alloc(256UL * 64 * 512 * 2);
    u16* xT1  = (u16*)alloc(256UL * 512 * 64 * 2);
    u16* mi2  = (u16*)alloc(256UL * 64 * 512 * 2);
    u16* xT2  = (u16*)alloc(256UL * 512 * 64 * 2);
    u16* x1   = (u16*)alloc(256UL * 64 * 512 * 2);
    u16* x1b  = (u16*)alloc(256UL * 64 * 512 * 2);
    u16* adjA = (u16*)alloc(256UL * 12 * 64 * 64 * 2);
    u16* adjB = (u16*)alloc(256UL * 12 * 64 * 64 * 2);
    u16* wf0  = (u16*)alloc(208UL * 32 * 64 * 8 * 2);
    u16* wf1  = (u16*)alloc(208UL * 32 * 64 * 8 * 2);
    u16* a1   = (u16*)alloc(1024UL * 6656 * 2);
    u16* a2   = (u16*)alloc(512UL * 6656 * 2);
    float* t2 = (float*)alloc(256UL * 2 * 512 * 4);

    k_wstack<<<1664, 256, 0, stream>>>(basis0, comb0, self0, wf0);
    k_wstack<<<1664, 256, 0, stream>>>(basis1, comb1, self1, wf1);
    k_adj<<<3072, 256, 0, stream>>>(adjm, adjA, adjB);
    k_prep<<<256, 256, 0, stream>>>(player, pAx, pAy, pBx, pBy, emb, cW, cb, inW, inb, mi1, mi2);
    k_cast<<<3840, 256, 0, stream>>>(enc, mi1, mi2);
    k_transpose<<<512, 256, 0, stream>>>(mi1, xT1);
    k_gemm0<<<256, 512, 0, stream>>>(mi1, xT1, adjA, wf0, x1);
    k_msgL1<<<1024, 256, 0, stream>>>(x1, adjA, a1, 4, 58, 59, 60, 61);
    k_gemmL1<<<dim3(16, 4), 512, 0, stream>>>(a1, wf1, 0, mi2, nullptr);
    k_transpose<<<512, 256, 0, stream>>>(mi2, xT2);
    k_gemm0<<<256, 512, 0, stream>>>(mi2, xT2, adjB, wf0, x1b);
    k_msgL1<<<512, 256, 0, stream>>>(x1b, adjB, a2, 2, 60, 62, 0, 0);
    k_gemmL1<<<dim3(8, 4), 512, 0, stream>>>(a2, wf1, 1, nullptr, t2);
    k_final<<<256, 64, 0, stream>>>(t2, typeW, typeb, (float*)d_out);
}

// Round 3
// 1852.092 us; speedup vs baseline: 1.3637x; 1.3637x over previous
//
#include <hip/hip_runtime.h>
#include <hip/hip_bf16.h>

typedef unsigned short u16;
typedef __attribute__((ext_vector_type(8))) short short8;
typedef __attribute__((ext_vector_type(4))) float floatx4;

__device__ __forceinline__ u16 f2bf(float f) {
    union { float f; unsigned u; } v; v.f = f;
    unsigned r = v.u + 0x7FFF + ((v.u >> 16) & 1);
    return (u16)(r >> 16);
}
__device__ __forceinline__ float bf2f(u16 h) {
    union { unsigned u; float f; } v; v.u = ((unsigned)h) << 16;
    return v.f;
}

using gp_t = const __attribute__((address_space(1))) unsigned int*;
using lp_t = __attribute__((address_space(3))) unsigned int*;
__device__ __forceinline__ void g2lds16(const void* g, void* l) {
    __builtin_amdgcn_global_load_lds((gp_t)g, (lp_t)l, 16, 0, 0);
}

// ---------------------------------------------------------------------------
// Wstack fragment builder (coalesced float4 basis reads).
// element (k,n) at: (k>>5)*16384 + (n>>4)*512 + ((k>>3)&3)*128 + (n&15)*8 + (k&7)
__global__ void k_wstack2(const float* __restrict__ basis, const float* __restrict__ comb,
                          const float* __restrict__ selfW, u16* __restrict__ wf) {
    int bi = blockIdx.x, t = threadIdx.x;
    int kr = t >> 7;             // 0..1
    int nb = (t & 127) * 4;      // n base
    for (int it = 0; it < 4; ++it) {
        int k = bi * 8 + it * 2 + kr;
        float v0, v1, v2, v3;
        if (k < 6144) {
            int r = k >> 9, h = k & 511;
            v0 = v1 = v2 = v3 = 0.f;
            for (int q = 0; q < 6; ++q) {
                float c = comb[r * 6 + q];
                const float4 bz = *(const float4*)(basis + ((size_t)(q * 512 + h)) * 512 + nb);
                v0 += c * bz.x; v1 += c * bz.y; v2 += c * bz.z; v3 += c * bz.w;
            }
        } else {
            int kk = k - 6144;
            v0 = selfW[(size_t)(nb + 0) * 512 + kk];
            v1 = selfW[(size_t)(nb + 1) * 512 + kk];
            v2 = selfW[(size_t)(nb + 2) * 512 + kk];
            v3 = selfW[(size_t)(nb + 3) * 512 + kk];
        }
        float vv[4] = {v0, v1, v2, v3};
        for (int i = 0; i < 4; ++i) {
            int n = nb + i;
            wf[(size_t)(k >> 5) * 16384 + (n >> 4) * 512 + ((k >> 3) & 3) * 128 + (n & 15) * 8 + (k & 7)] = f2bf(vv[i]);
        }
    }
}

// ---------------------------------------------------------------------------
// Adjacency prep: adjA raw ch r+1 (rgcn1); adjB updated+remapped (rgcn2).
__global__ void k_adj(const int* __restrict__ A, u16* __restrict__ adjA, u16* __restrict__ adjB) {
    int bi = blockIdx.x;          // b*12 + r
    int b = bi / 12, r = bi % 12;
    const int* Ab = A + (size_t)(b * 13 + (r + 1)) * 62 * 62;
    u16* oA = adjA + (size_t)bi * 64 * 64;
    u16* oB = adjB + (size_t)bi * 64 * 64;
    int t = threadIdx.x;
    int n = t >> 2, m0 = (t & 3) * 16;
    for (int i = 0; i < 16; ++i) {
        int m = m0 + i;
        u16 va = 0;
        if (n < 62 && m < 62) va = Ab[n * 62 + m] ? 0x3F80 : 0;
        oA[n * 64 + m] = va;
        u16 vb = 0;
        if (n < 63 && m < 63) {
            int oi = (n == 62) ? 63 : n, oj = (m == 62) ? 63 : m;
            int val = 0;
            if (oi < 62 && oj < 62) val = Ab[oi * 62 + oj] ? 1 : 0;
            int lo = (oi < oj) ? oi : oj, hi = (oi < oj) ? oj : oi;
            if (hi == lo + 2) {
                int p = (lo >> 1) & 1;
                int chp = ((lo & 1) == 0) ? (p ? 12 : 11) : (p ? 11 : 12);
                if (r + 1 == chp) val = 1;
            }
            vb = val ? 0x3F80 : 0;
        }
        oB[n * 64 + m] = vb;
    }
}

// ---------------------------------------------------------------------------
// initial embedding -> mi1 rows 60..63 ; mi2 rows 62,63
__global__ void k_prep(const int* __restrict__ player,
                       const float* __restrict__ pAx, const float* __restrict__ pAy,
                       const float* __restrict__ pBx, const float* __restrict__ pBy,
                       const float* __restrict__ emb, const float* __restrict__ cW,
                       const float* __restrict__ cb, const float* __restrict__ inW,
                       const float* __restrict__ inb,
                       u16* __restrict__ mi1, u16* __restrict__ mi2) {
    int b = blockIdx.x, t = threadIdx.x;
    __shared__ float feat[2][64];
    if (t < 64) {
        int j = t >> 5, d = t & 31;
        float X = j ? pBx[b] : pAx[b];
        float Y = j ? pBy[b] : pAy[b];
        feat[j][d] = fmaxf(cW[d * 2] * X + cW[d * 2 + 1] * Y + cb[d], 0.f);
        feat[j][32 + d] = emb[player[b * 2 + j] * 32 + d];
    }
    __syncthreads();
    for (int h = t; h < 512; h += 256) {
        float a0 = inb[h], a1 = inb[h];
        const float* wrow = inW + h * 64;
        #pragma unroll
        for (int d = 0; d < 64; ++d) {
            float wv = wrow[d];
            a0 += wv * feat[0][d];
            a1 += wv * feat[1][d];
        }
        u16 v0 = f2bf(a0), v1 = f2bf(a1);
        size_t base = (size_t)b * 64 * 512;
        mi1[base + 60 * 512 + h] = v0;
        mi1[base + 61 * 512 + h] = v1;
        mi1[base + 62 * 512 + h] = 0;
        mi1[base + 63 * 512 + h] = 0;
        mi2[base + 62 * 512 + h] = v1;
        mi2[base + 63 * 512 + h] = 0;
    }
}

// enc f32 -> mi1 rows 0..59 ; mi2 rows 0..57
__global__ void k_cast(const float* __restrict__ enc, u16* __restrict__ mi1, u16* __restrict__ mi2) {
    long long e = ((long long)blockIdx.x * 256 + threadIdx.x) * 8;
    if (e >= 256LL * 60 * 512) return;
    int b = (int)(e / (60 * 512));
    int rm = (int)(e % (60 * 512));
    int n = rm / 512, h = rm % 512;
    for (int i = 0; i < 8; ++i) {
        u16 v = f2bf(enc[e + i]);
        mi1[((size_t)b * 64 + n) * 512 + h + i] = v;
        if (n < 58) mi2[((size_t)b * 64 + n) * 512 + h + i] = v;
    }
}

// x (B,64,512) -> A chunk x-columns. grid = chunkB*16 blocks.
__global__ void k_xcopy(const u16* __restrict__ mi, u16* __restrict__ A, int c0) {
    long long e = ((long long)blockIdx.x * 256 + threadIdx.x) * 8;
    int rl = (int)(e / 512), h = (int)(e % 512);
    *(short8*)(A + (size_t)rl * 6656 + 6144 + h) =
        *(const short8*)(mi + ((size_t)c0 * 64 + rl) * 512 + h);
}

// (B,64,512) -> (B,512,64) transpose
__global__ void k_transpose(const u16* __restrict__ in, u16* __restrict__ out) {
    int b = blockIdx.x >> 1, half = blockIdx.x & 1;
    __shared__ __align__(16) u16 tile[64][264];
    int t = threadIdx.x;
    int m = t >> 2, c0 = (t & 3) * 64;
    const u16* ip = in + ((size_t)b * 64 + m) * 512 + half * 256 + c0;
    for (int i = 0; i < 64; i += 8)
        *(short8*)&tile[m][c0 + i] = *(const short8*)(ip + i);
    __syncthreads();
    int h = t;
    u16* op = out + ((size_t)b * 512 + half * 256 + h) * 64;
    for (int mm = 0; mm < 64; mm += 8) {
        short8 ov;
        #pragma unroll
        for (int i = 0; i < 8; ++i) ov[i] = (short)tile[mm + i][h];
        *(short8*)(op + mm) = ov;
    }
}

// ---------------------------------------------------------------------------
// msg builder: block per (chunk-batch, r). msg_r = adj_r @ x (64x512) -> A cols r*512..
__global__ __launch_bounds__(256)
void k_msg(const u16* __restrict__ xT, const u16* __restrict__ adj, u16* __restrict__ A, int c0) {
    int bi = blockIdx.x;
    int bl = bi / 12, r = bi % 12;       // bl = local batch in chunk
    int b = c0 + bl;
    int t = threadIdx.x, lane = t & 63, w = t >> 6;
    int l15 = lane & 15, lq = lane >> 4;
    __shared__ __align__(16) u16 stg[4][16 * 136];
    const u16* adjr = adj + ((size_t)b * 12 + r) * 4096;
    const u16* xTb = xT + (size_t)b * 512 * 64;
    short8 af0 = *(const short8*)(adjr + (w * 16 + l15) * 64 + lq * 8);
    short8 af1 = *(const short8*)(adjr + (w * 16 + l15) * 64 + 32 + lq * 8);
    for (int ct = 0; ct < 4; ++ct) {
        floatx4 acc[8];
        #pragma unroll
        for (int i = 0; i < 8; ++i) acc[i] = (floatx4)(0.f);
        #pragma unroll
        for (int nt = 0; nt < 8; ++nt) {
            const u16* bp = xTb + (ct * 128 + nt * 16 + l15) * 64 + lq * 8;
            short8 b0 = *(const short8*)bp;
            short8 b1 = *(const short8*)(bp + 32);
            acc[nt] = __builtin_amdgcn_mfma_f32_16x16x32_bf16(af0, b0, acc[nt], 0, 0, 0);
            acc[nt] = __builtin_amdgcn_mfma_f32_16x16x32_bf16(af1, b1, acc[nt], 0, 0, 0);
        }
        #pragma unroll
        for (int nt = 0; nt < 8; ++nt)
            #pragma unroll
            for (int rr = 0; rr < 4; ++rr)
                stg[w][(lq * 4 + rr) * 136 + nt * 16 + l15] = f2bf(acc[nt][rr]);
        int row = lane >> 2, cb = (lane & 3) * 32;
        u16* gp = A + ((size_t)(bl * 64 + w * 16 + row)) * 6656 + r * 512 + ct * 128 + cb;
        #pragma unroll
        for (int jj = 0; jj < 4; ++jj)
            *(short8*)(gp + jj * 8) = *(const short8*)&stg[w][row * 136 + cb + jj * 8];
    }
}

// ---------------------------------------------------------------------------
// Big GEMM: out = relu(A @ Wstack). A rows local to chunk; out pre-offset.
__global__ __launch_bounds__(256)
void k_bigemm(const u16* __restrict__ A, const u16* __restrict__ wf, u16* __restrict__ out) {
    int ct = blockIdx.x, mb = blockIdx.y;
    int t = threadIdx.x, lane = t & 63, w = t >> 6;
    int wm = w & 1, wn = w >> 1;
    int l15 = lane & 15, lq = lane >> 4;
    __shared__ __align__(16) u16 As[128 * 32];
    __shared__ __align__(16) u16 Bs[8 * 64 * 8];
    floatx4 acc[4][4];
    #pragma unroll
    for (int i = 0; i < 4; ++i)
        #pragma unroll
        for (int j = 0; j < 4; ++j) acc[i][j] = (floatx4)(0.f);

    int slot0 = t, slot1 = 256 + t;
    const u16* Ag0 = A + (size_t)(mb * 128 + (slot0 >> 2)) * 6656 + (slot0 & 3) * 8;
    const u16* Ag1 = A + (size_t)(mb * 128 + (slot1 >> 2)) * 6656 + (slot1 & 3) * 8;
    const u16* Bg0 = wf + (size_t)ct * 4096 + slot0 * 8;
    const u16* Bg1 = wf + (size_t)ct * 4096 + slot1 * 8;
    u16* AsB0 = As + (size_t)(w * 64) * 8;
    u16* AsB1 = As + (size_t)(256 + w * 64) * 8;
    u16* BsB0 = Bs + (size_t)(w * 64) * 8;
    u16* BsB1 = Bs + (size_t)(256 + w * 64) * 8;

    for (int gk = 0; gk < 208; ++gk) {
        __syncthreads();
        g2lds16(Ag0 + gk * 32, AsB0);
        g2lds16(Ag1 + gk * 32, AsB1);
        g2lds16(Bg0 + (size_t)gk * 16384, BsB0);
        g2lds16(Bg1 + (size_t)gk * 16384, BsB1);
        __syncthreads();
        short8 af[4], bfr[4];
        #pragma unroll
        for (int mt = 0; mt < 4; ++mt)
            af[mt] = *(const short8*)&As[(wm * 64 + mt * 16 + l15) * 32 + lq * 8];
        #pragma unroll
        for (int nt = 0; nt < 4; ++nt)
            bfr[nt] = *(const short8*)&Bs[((wn * 4 + nt) * 64 + lane) * 8];
        #pragma unroll
        for (int mt = 0; mt < 4; ++mt)
            #pragma unroll
            for (int nt = 0; nt < 4; ++nt)
                acc[mt][nt] = __builtin_amdgcn_mfma_f32_16x16x32_bf16(af[mt], bfr[nt], acc[mt][nt], 0, 0, 0);
    }
    size_t rbase = (size_t)mb * 128 + wm * 64;
    #pragma unroll
    for (int mt = 0; mt < 4; ++mt)
        #pragma unroll
        for (int nt = 0; nt < 4; ++nt)
            #pragma unroll
            for (int rr = 0; rr < 4; ++rr) {
                size_t row = rbase + mt * 16 + lq * 4 + rr;
                int col = ct * 128 + wn * 64 + nt * 16 + l15;
                out[row * 512 + col] = f2bf(fmaxf(acc[mt][nt][rr], 0.f));
            }
}

// ---------------------------------------------------------------------------
// Layer-1 msg rows: Aout[b*nout+ni][k] = [msg_r(node)..., x(node)]
__global__ void k_msgL1(const u16* __restrict__ x1, const u16* __restrict__ adj,
                        u16* __restrict__ Aout, int nout, int n0, int n1, int n2, int n3) {
    int bi = blockIdx.x;
    int b = bi / nout, ni = bi % nout;
    int nds[4] = {n0, n1, n2, n3};
    int n = nds[ni];
    int t = threadIdx.x;
    __shared__ u16 adjrow[12 * 64];
    const u16* ab = adj + (size_t)b * 12 * 64 * 64 + n * 64;
    for (int i = t; i < 768; i += 256) adjrow[i] = ab[(i >> 6) * 4096 + (i & 63)];
    __syncthreads();
    float s0[12], s1[12];
    #pragma unroll
    for (int r = 0; r < 12; ++r) { s0[r] = 0.f; s1[r] = 0.f; }
    const u16* xb = x1 + (size_t)b * 64 * 512;
    for (int m = 0; m < 64; ++m) {
        float xv0 = bf2f(xb[m * 512 + t]);
        float xv1 = bf2f(xb[m * 512 + t + 256]);
        #pragma unroll
        for (int r = 0; r < 12; ++r) {
            float av = bf2f(adjrow[r * 64 + m]);
            s0[r] += av * xv0;
            s1[r] += av * xv1;
        }
    }
    u16* Ar = Aout + (size_t)bi * 6656;
    #pragma unroll
    for (int r = 0; r < 12; ++r) {
        Ar[r * 512 + t]       = f2bf(s0[r]);
        Ar[r * 512 + t + 256] = f2bf(s1[r]);
    }
    Ar[6144 + t]       = xb[n * 512 + t];
    Ar[6144 + t + 256] = xb[n * 512 + t + 256];
}

// Layer-1 GEMM, barrier-free. grid (ct=4, mb). mode 0 -> mi2 rows 58..61; mode 1 -> t2.
__global__ __launch_bounds__(256)
void k_gemmL1(const u16* __restrict__ A, const u16* __restrict__ wf,
              int mode, u16* __restrict__ mi2, float* __restrict__ t2) {
    int ct = blockIdx.x, mb = blockIdx.y;
    int t = threadIdx.x, lane = t & 63, wr = t >> 6;
    int l15 = lane & 15, lq = lane >> 4;
    floatx4 acc[8];
    #pragma unroll
    for (int i = 0; i < 8; ++i) acc[i] = (floatx4)(0.f);
    const u16* Ar = A + (size_t)(mb * 64 + wr * 16 + l15) * 6656 + lq * 8;
    const u16* Wb = wf + (size_t)ct * 4096 + lane * 8;
    #pragma unroll 2
    for (int gk = 0; gk < 208; ++gk) {
        short8 af = *(const short8*)(Ar + gk * 32);
        const u16* wp = Wb + (size_t)gk * 16384;
        #pragma unroll
        for (int nt = 0; nt < 8; ++nt) {
            short8 bfg = *(const short8*)(wp + (size_t)nt * 512);
            acc[nt] = __builtin_amdgcn_mfma_f32_16x16x32_bf16(af, bfg, acc[nt], 0, 0, 0);
        }
    }
    #pragma unroll
    for (int nt = 0; nt < 8; ++nt)
        #pragma unroll
        for (int rr = 0; rr < 4; ++rr) {
            int Mrow = mb * 64 + wr * 16 + lq * 4 + rr;
            int col = ct * 128 + nt * 16 + l15;
            float v = 1.f / (1.f + __expf(-acc[nt][rr]));
            if (mode == 0) {
                int b = Mrow >> 2, nidx = Mrow & 3;
                mi2[((size_t)b * 64 + 58 + nidx) * 512 + col] = f2bf(v);
            } else {
                t2[(size_t)Mrow * 512 + col] = v;
            }
        }
}

// logits = [black|white] @ type_W^T + type_b
__global__ void k_final(const float* __restrict__ t2, const float* __restrict__ tW,
                        const float* __restrict__ tb, float* __restrict__ outp) {
    int b = blockIdx.x, l = threadIdx.x;   // 64 threads
    float a[11];
    #pragma unroll
    for (int j = 0; j < 11; ++j) a[j] = 0.f;
    for (int it = 0; it < 16; ++it) {
        int h = it * 64 + l;
        float c = (h < 512) ? t2[(b * 2 + 1) * 512 + h] : t2[(b * 2 + 0) * 512 + (h - 512)];
        #pragma unroll
        for (int j = 0; j < 11; ++j) a[j] += c * tW[j * 1024 + h];
    }
    #pragma unroll
    for (int j = 0; j < 11; ++j) {
        float v = a[j];
        for (int off = 32; off > 0; off >>= 1) v += __shfl_down(v, off, 64);
        if (l == 0) outp[b * 11 + j] = v + tb[j];
    }
}

// ---------------------------------------------------------------------------
extern "C" void kernel_launch(void* const* d_in, const int* in_sizes, int n_in,
                              void* d_out, int out_size, void* d_ws, size_t ws_size,
                              hipStream_t stream) {
    const int*   player = (const int*)d_in[0];
    const float* enc    = (const float*)d_in[2];
    const int*   adjm   = (const int*)d_in[3];
    const float* pAx    = (const float*)d_in[4];
    const float* pAy    = (const float*)d_in[5];
    const float* pBx    = (const float*)d_in[6];
    const float* pBy    = (const float*)d_in[7];
    const float* emb    = (const float*)d_in[8];
    const float* cW     = (const float*)d_in[9];
    const float* cb     = (const float*)d_in[10];
    const float* inW    = (const float*)d_in[11];
    const float* inb    = (const float*)d_in[12];
    const float* basis0 = (const float*)d_in[13];
    const float* comb0  = (const float*)d_in[14];
    const float* self0  = (const float*)d_in[15];
    const float* basis1 = (const float*)d_in[16];
    const float* comb1  = (const float*)d_in[17];
    const float* self1  = (const float*)d_in[18];
    const float* typeW  = (const float*)d_in[19];
    const float* typeb  = (const float*)d_in[20];

    char* ws = (char*)d_ws;
    size_t off = 0;
    auto alloc = [&](size_t bytes) -> void* {
        void* p = ws + off;
        off = (off + bytes + 255) & ~(size_t)255;
        return p;
    };
    u16* mi1  = (u16*)alloc(256UL * 64 * 512 * 2);
    u16* mi2  = (u16*)alloc(256UL * 64 * 512 * 2);
    u16* xT   = (u16*)alloc(256UL * 512 * 64 * 2);
    u16* x12  = (u16*)alloc(256UL * 64 * 512 * 2);
    u16* adjA = (u16*)alloc(256UL * 12 * 64 * 64 * 2);
    u16* adjB = (u16*)alloc(256UL * 12 * 64 * 64 * 2);
    u16* wf0  = (u16*)alloc(208UL * 32 * 64 * 8 * 2);
    u16* wf1  = (u16*)alloc(208UL * 32 * 64 * 8 * 2);
    u16* a1   = (u16*)alloc(1024UL * 6656 * 2);
    float* t2 = (float*)alloc(512UL * 512 * 4);

    // A chunk buffer: whatever remains, in power-of-two batches.
    size_t remain = (ws_size > off) ? (ws_size - off) : 0;
    int chunkB = 256;
    while (chunkB > 2 && (size_t)chunkB * 64 * 6656 * 2 > remain) chunkB >>= 1;
    u16* A = (u16*)(ws + off);

    k_wstack2<<<832, 256, 0, stream>>>(basis0, comb0, self0, wf0);
    k_wstack2<<<832, 256, 0, stream>>>(basis1, comb1, self1, wf1);
    k_adj<<<3072, 256, 0, stream>>>(adjm, adjA, adjB);
    k_prep<<<256, 256, 0, stream>>>(player, pAx, pAy, pBx, pBy, emb, cW, cb, inW, inb, mi1, mi2);
    k_cast<<<3840, 256, 0, stream>>>(enc, mi1, mi2);

    // rgcn pass 1, layer 0 (chunked over batches)
    k_transpose<<<512, 256, 0, stream>>>(mi1, xT);
    for (int c0 = 0; c0 < 256; c0 += chunkB) {
        k_xcopy<<<chunkB * 16, 256, 0, stream>>>(mi1, A, c0);
        k_msg<<<chunkB * 12, 256, 0, stream>>>(xT, adjA, A, c0);
        k_bigemm<<<dim3(4, chunkB / 2), 256, 0, stream>>>(A, wf0, x12 + (size_t)c0 * 64 * 512);
    }
    // rgcn pass 1, layer 1 (4 nodes)
    k_msgL1<<<1024, 256, 0, stream>>>(x12, adjA, a1, 4, 58, 59, 60, 61);
    k_gemmL1<<<dim3(4, 16), 256, 0, stream>>>(a1, wf1, 0, mi2, nullptr);

    // rgcn pass 2, layer 0 (chunked)
    k_transpose<<<512, 256, 0, stream>>>(mi2, xT);
    for (int c0 = 0; c0 < 256; c0 += chunkB) {
        k_xcopy<<<chunkB * 16, 256, 0, stream>>>(mi2, A, c0);
        k_msg<<<chunkB * 12, 256, 0, stream>>>(xT, adjB, A, c0);
        k_bigemm<<<dim3(4, chunkB / 2), 256, 0, stream>>>(A, wf0, x12 + (size_t)c0 * 64 * 512);
    }
    // rgcn pass 2, layer 1 (2 nodes)
    k_msgL1<<<512, 256, 0, stream>>>(x12, adjB, a1, 2, 60, 62, 0, 0);
    k_gemmL1<<<dim3(4, 8), 256, 0, stream>>>(a1, wf1, 1, nullptr, t2);
    k_final<<<256, 64, 0, stream>>>(t2, typeW, typeb, (float*)d_out);
}

// Round 4
// 1653.437 us; speedup vs baseline: 1.5276x; 1.1201x over previous
//
#include <hip/hip_runtime.h>
#include <hip/hip_bf16.h>

typedef unsigned short u16;
typedef __attribute__((ext_vector_type(4))) short short4v;
typedef __attribute__((ext_vector_type(8))) short short8;
typedef __attribute__((ext_vector_type(4))) float floatx4;

__device__ __forceinline__ u16 f2bf(float f) {
    union { float f; unsigned u; } v; v.f = f;
    unsigned r = v.u + 0x7FFF + ((v.u >> 16) & 1);
    return (u16)(r >> 16);
}

using gp_t = const __attribute__((address_space(1))) unsigned int*;
using lp_t = __attribute__((address_space(3))) unsigned int*;
__device__ __forceinline__ void g2lds16(const void* g, void* l) {
    __builtin_amdgcn_global_load_lds((gp_t)g, (lp_t)l, 16, 0, 0);
}

// ---------------------------------------------------------------------------
// Wstack fragment builder (validated rounds 1-3).
// element (k,n) at: (k>>5)*16384 + (n>>4)*512 + ((k>>3)&3)*128 + (n&15)*8 + (k&7)
__global__ void k_wstack2(const float* __restrict__ basis, const float* __restrict__ comb,
                          const float* __restrict__ selfW, u16* __restrict__ wf) {
    int bi = blockIdx.x, t = threadIdx.x;
    int kr = t >> 7;             // 0..1
    int nb = (t & 127) * 4;      // n base
    for (int it = 0; it < 4; ++it) {
        int k = bi * 8 + it * 2 + kr;
        float v0, v1, v2, v3;
        if (k < 6144) {
            int r = k >> 9, h = k & 511;
            v0 = v1 = v2 = v3 = 0.f;
            for (int q = 0; q < 6; ++q) {
                float c = comb[r * 6 + q];
                const float4 bz = *(const float4*)(basis + ((size_t)(q * 512 + h)) * 512 + nb);
                v0 += c * bz.x; v1 += c * bz.y; v2 += c * bz.z; v3 += c * bz.w;
            }
        } else {
            int kk = k - 6144;
            v0 = selfW[(size_t)(nb + 0) * 512 + kk];
            v1 = selfW[(size_t)(nb + 1) * 512 + kk];
            v2 = selfW[(size_t)(nb + 2) * 512 + kk];
            v3 = selfW[(size_t)(nb + 3) * 512 + kk];
        }
        float vv[4] = {v0, v1, v2, v3};
        for (int i = 0; i < 4; ++i) {
            int n = nb + i;
            wf[(size_t)(k >> 5) * 16384 + (n >> 4) * 512 + ((k >> 3) & 3) * 128 + (n & 15) * 8 + (k & 7)] = f2bf(vv[i]);
        }
    }
}

// ---------------------------------------------------------------------------
// Adjacency prep (validated): adjA raw ch r+1; adjB updated+remapped.
__global__ void k_adj(const int* __restrict__ A, u16* __restrict__ adjA, u16* __restrict__ adjB) {
    int bi = blockIdx.x;          // b*12 + r
    int b = bi / 12, r = bi % 12;
    const int* Ab = A + (size_t)(b * 13 + (r + 1)) * 62 * 62;
    u16* oA = adjA + (size_t)bi * 64 * 64;
    u16* oB = adjB + (size_t)bi * 64 * 64;
    int t = threadIdx.x;
    int n = t >> 2, m0 = (t & 3) * 16;
    for (int i = 0; i < 16; ++i) {
        int m = m0 + i;
        u16 va = 0;
        if (n < 62 && m < 62) va = Ab[n * 62 + m] ? 0x3F80 : 0;
        oA[n * 64 + m] = va;
        u16 vb = 0;
        if (n < 63 && m < 63) {
            int oi = (n == 62) ? 63 : n, oj = (m == 62) ? 63 : m;
            int val = 0;
            if (oi < 62 && oj < 62) val = Ab[oi * 62 + oj] ? 1 : 0;
            int lo = (oi < oj) ? oi : oj, hi = (oi < oj) ? oj : oi;
            if (hi == lo + 2) {
                int p = (lo >> 1) & 1;
                int chp = ((lo & 1) == 0) ? (p ? 12 : 11) : (p ? 11 : 12);
                if (r + 1 == chp) val = 1;
            }
            vb = val ? 0x3F80 : 0;
        }
        oB[n * 64 + m] = vb;
    }
}

// ---------------------------------------------------------------------------
// initial embedding -> mi1 rows 60..63 ; mi2 rows 62,63
__global__ void k_prep(const int* __restrict__ player,
                       const float* __restrict__ pAx, const float* __restrict__ pAy,
                       const float* __restrict__ pBx, const float* __restrict__ pBy,
                       const float* __restrict__ emb, const float* __restrict__ cW,
                       const float* __restrict__ cb, const float* __restrict__ inW,
                       const float* __restrict__ inb,
                       u16* __restrict__ mi1, u16* __restrict__ mi2) {
    int b = blockIdx.x, t = threadIdx.x;
    __shared__ float feat[2][64];
    if (t < 64) {
        int j = t >> 5, d = t & 31;
        float X = j ? pBx[b] : pAx[b];
        float Y = j ? pBy[b] : pAy[b];
        feat[j][d] = fmaxf(cW[d * 2] * X + cW[d * 2 + 1] * Y + cb[d], 0.f);
        feat[j][32 + d] = emb[player[b * 2 + j] * 32 + d];
    }
    __syncthreads();
    for (int h = t; h < 512; h += 256) {
        float a0 = inb[h], a1 = inb[h];
        const float* wrow = inW + h * 64;
        #pragma unroll
        for (int d = 0; d < 64; ++d) {
            float wv = wrow[d];
            a0 += wv * feat[0][d];
            a1 += wv * feat[1][d];
        }
        u16 v0 = f2bf(a0), v1 = f2bf(a1);
        size_t base = (size_t)b * 64 * 512;
        mi1[base + 60 * 512 + h] = v0;
        mi1[base + 61 * 512 + h] = v1;
        mi1[base + 62 * 512 + h] = 0;
        mi1[base + 63 * 512 + h] = 0;
        mi2[base + 62 * 512 + h] = v1;
        mi2[base + 63 * 512 + h] = 0;
    }
}

// enc f32 -> mi1 rows 0..59 ; mi2 rows 0..57
__global__ void k_cast(const float* __restrict__ enc, u16* __restrict__ mi1, u16* __restrict__ mi2) {
    long long e = ((long long)blockIdx.x * 256 + threadIdx.x) * 8;
    if (e >= 256LL * 60 * 512) return;
    int b = (int)(e / (60 * 512));
    int rm = (int)(e % (60 * 512));
    int n = rm / 512, h = rm % 512;
    for (int i = 0; i < 8; ++i) {
        u16 v = f2bf(enc[e + i]);
        mi1[((size_t)b * 64 + n) * 512 + h + i] = v;
        if (n < 58) mi2[((size_t)b * 64 + n) * 512 + h + i] = v;
    }
}

// ---------------------------------------------------------------------------
// Fused RGCN layer: per block (batch b, col-tile ct of 128).
//   Z_r = x @ W_r  (64x128, MFMA, W streamed from global fragment-order)
//   y  += adj_r @ Z_r   (aggregation via LDS round-trip), plus Z_self direct.
// mode 0: relu -> o16 (b,64,512); mode 1: sigmoid rows 58..61 -> o16 (mi2);
// mode 2: sigmoid rows 60,62 -> o32 (t2 rows b*2, b*2+1).
__global__ __launch_bounds__(512, 1)
void k_fused(const u16* __restrict__ x, const u16* __restrict__ adj,
             const u16* __restrict__ wf, int mode,
             u16* __restrict__ o16, float* __restrict__ o32) {
    int b = blockIdx.x >> 2, ct = blockIdx.x & 3;
    int t = threadIdx.x, lane = t & 63, w = t >> 6;
    int wm = w & 3, wn = w >> 2;            // wm: 16-row band, wn: 64-col band
    int l15 = lane & 15, lq = lane >> 4;

    __shared__ __align__(16) u16 xs[64 * 520];    // x[m][h], pitch 520
    __shared__ __align__(16) u16 zs[128 * 72];    // Z^T: [col][m], pitch 72
    __shared__ __align__(16) u16 adjs[64 * 72];   // adj_r[n][m], pitch 72

    const u16* xb = x + (size_t)b * 64 * 512;
    const u16* adjb = adj + (size_t)b * 12 * 4096;

    // stage x: one g2lds16 per row (wave-uniform LDS base, 64 lanes x 16B = 1 row)
    {
        int r0 = w * 8;
        #pragma unroll
        for (int j = 0; j < 8; ++j)
            g2lds16(xb + (r0 + j) * 512 + lane * 8, xs + (r0 + j) * 520);
    }

    floatx4 ay[4];
    #pragma unroll
    for (int i = 0; i < 4; ++i) ay[i] = (floatx4)(0.f);

    const u16* wbase = wf + (size_t)(ct * 8 + wn * 4) * 512 + lane * 8;

    for (int r = 0; r < 13; ++r) {
        if (r < 12) {
            int row = t >> 3, c8 = (t & 7) * 8;
            *(short8*)&adjs[row * 72 + c8] = *(const short8*)(adjb + r * 4096 + row * 64 + c8);
        }
        __syncthreads();   // xs (r==0) + adjs ready; zs from prev r consumed

        // Z-phase: az = x @ W_r tile (16 rows x 64 cols per wave)
        floatx4 az[4];
        #pragma unroll
        for (int i = 0; i < 4; ++i) az[i] = (floatx4)(0.f);
        const u16* wr = wbase + (size_t)(r * 16) * 16384;
        for (int ks = 0; ks < 16; ++ks) {
            short8 af = *(const short8*)&xs[(wm * 16 + l15) * 520 + ks * 32 + lq * 8];
            const u16* wp = wr + (size_t)ks * 16384;
            #pragma unroll
            for (int i = 0; i < 4; ++i) {
                short8 bfg = *(const short8*)(wp + (size_t)i * 512);
                az[i] = __builtin_amdgcn_mfma_f32_16x16x32_bf16(af, bfg, az[i], 0, 0, 0);
            }
        }

        if (r < 12) {
            // write Z^T to zs: lane holds rows m = wm*16+lq*4+rr, col = wn*64+i*16+l15
            #pragma unroll
            for (int i = 0; i < 4; ++i) {
                short4v pk;
                #pragma unroll
                for (int rr = 0; rr < 4; ++rr) pk[rr] = (short)f2bf(az[i][rr]);
                *(short4v*)&zs[(wn * 64 + i * 16 + l15) * 72 + wm * 16 + lq * 4] = pk;
            }
            __syncthreads();   // zs ready
            // aggregation: ay += adj_r @ Z_r
            #pragma unroll
            for (int k2 = 0; k2 < 2; ++k2) {
                short8 af2 = *(const short8*)&adjs[(wm * 16 + l15) * 72 + k2 * 32 + lq * 8];
                #pragma unroll
                for (int i = 0; i < 4; ++i) {
                    short8 bf2 = *(const short8*)&zs[(wn * 64 + i * 16 + l15) * 72 + k2 * 32 + lq * 8];
                    ay[i] = __builtin_amdgcn_mfma_f32_16x16x32_bf16(af2, bf2, ay[i], 0, 0, 0);
                }
            }
            __syncthreads();   // agg done; adjs/zs free for next r
        } else {
            // self term: same row index space -> direct add
            #pragma unroll
            for (int i = 0; i < 4; ++i) ay[i] += az[i];
        }
    }

    // epilogue
    #pragma unroll
    for (int i = 0; i < 4; ++i)
        #pragma unroll
        for (int rr = 0; rr < 4; ++rr) {
            int row = wm * 16 + lq * 4 + rr;
            int col = ct * 128 + wn * 64 + i * 16 + l15;
            float v = ay[i][rr];
            if (mode == 0) {
                o16[((size_t)b * 64 + row) * 512 + col] = f2bf(fmaxf(v, 0.f));
            } else {
                float s = 1.f / (1.f + __expf(-v));
                if (mode == 1) {
                    if (row >= 58 && row <= 61)
                        o16[((size_t)b * 64 + row) * 512 + col] = f2bf(s);
                } else {
                    if (row == 60) o32[(size_t)(b * 2) * 512 + col] = s;
                    if (row == 62) o32[(size_t)(b * 2 + 1) * 512 + col] = s;
                }
            }
        }
}

// logits = [black|white] @ type_W^T + type_b
__global__ void k_final(const float* __restrict__ t2, const float* __restrict__ tW,
                        const float* __restrict__ tb, float* __restrict__ outp) {
    int b = blockIdx.x, l = threadIdx.x;   // 64 threads
    float a[11];
    #pragma unroll
    for (int j = 0; j < 11; ++j) a[j] = 0.f;
    for (int it = 0; it < 16; ++it) {
        int h = it * 64 + l;
        float c = (h < 512) ? t2[(b * 2 + 1) * 512 + h] : t2[(b * 2 + 0) * 512 + (h - 512)];
        #pragma unroll
        for (int j = 0; j < 11; ++j) a[j] += c * tW[j * 1024 + h];
    }
    #pragma unroll
    for (int j = 0; j < 11; ++j) {
        float v = a[j];
        for (int off = 32; off > 0; off >>= 1) v += __shfl_down(v, off, 64);
        if (l == 0) outp[b * 11 + j] = v + tb[j];
    }
}

// ---------------------------------------------------------------------------
extern "C" void kernel_launch(void* const* d_in, const int* in_sizes, int n_in,
                              void* d_out, int out_size, void* d_ws, size_t ws_size,
                              hipStream_t stream) {
    const int*   player = (const int*)d_in[0];
    const float* enc    = (const float*)d_in[2];
    const int*   adjm   = (const int*)d_in[3];
    const float* pAx    = (const float*)d_in[4];
    const float* pAy    = (const float*)d_in[5];
    const float* pBx    = (const float*)d_in[6];
    const float* pBy    = (const float*)d_in[7];
    const float* emb    = (const float*)d_in[8];
    const float* cW     = (const float*)d_in[9];
    const float* cb     = (const float*)d_in[10];
    const float* inW    = (const float*)d_in[11];
    const float* inb    = (const float*)d_in[12];
    const float* basis0 = (const float*)d_in[13];
    const float* comb0  = (const float*)d_in[14];
    const float* self0  = (const float*)d_in[15];
    const float* basis1 = (const float*)d_in[16];
    const float* comb1  = (const float*)d_in[17];
    const float* self1  = (const float*)d_in[18];
    const float* typeW  = (const float*)d_in[19];
    const float* typeb  = (const float*)d_in[20];

    char* ws = (char*)d_ws;
    size_t off = 0;
    auto alloc = [&](size_t bytes) -> void* {
        void* p = ws + off;
        off = (off + bytes + 255) & ~(size_t)255;
        return p;
    };
    u16* mi1  = (u16*)alloc(256UL * 64 * 512 * 2);
    u16* mi2  = (u16*)alloc(256UL * 64 * 512 * 2);
    u16* x12  = (u16*)alloc(256UL * 64 * 512 * 2);
    u16* x12b = (u16*)alloc(256UL * 64 * 512 * 2);
    u16* adjA = (u16*)alloc(256UL * 12 * 64 * 64 * 2);
    u16* adjB = (u16*)alloc(256UL * 12 * 64 * 64 * 2);
    u16* wf0  = (u16*)alloc(208UL * 32 * 64 * 8 * 2);
    u16* wf1  = (u16*)alloc(208UL * 32 * 64 * 8 * 2);
    float* t2 = (float*)alloc(512UL * 512 * 4);

    k_wstack2<<<832, 256, 0, stream>>>(basis0, comb0, self0, wf0);
    k_wstack2<<<832, 256, 0, stream>>>(basis1, comb1, self1, wf1);
    k_adj<<<3072, 256, 0, stream>>>(adjm, adjA, adjB);
    k_prep<<<256, 256, 0, stream>>>(player, pAx, pAy, pBx, pBy, emb, cW, cb, inW, inb, mi1, mi2);
    k_cast<<<3840, 256, 0, stream>>>(enc, mi1, mi2);

    // rgcn pass 1
    k_fused<<<1024, 512, 0, stream>>>(mi1, adjA, wf0, 0, x12, nullptr);
    k_fused<<<1024, 512, 0, stream>>>(x12, adjA, wf1, 1, mi2, nullptr);
    // rgcn pass 2
    k_fused<<<1024, 512, 0, stream>>>(mi2, adjB, wf0, 0, x12b, nullptr);
    k_fused<<<1024, 512, 0, stream>>>(x12b, adjB, wf1, 2, nullptr, t2);

    k_final<<<256, 64, 0, stream>>>(t2, typeW, typeb, (float*)d_out);
}

// Round 5
// 1351.231 us; speedup vs baseline: 1.8692x; 1.2237x over previous
//
#include <hip/hip_runtime.h>
#include <hip/hip_bf16.h>

typedef unsigned short u16;
typedef __attribute__((ext_vector_type(4))) short short4v;
typedef __attribute__((ext_vector_type(8))) short short8;
typedef __attribute__((ext_vector_type(4))) float floatx4;

__device__ __forceinline__ u16 f2bf(float f) {
    union { float f; unsigned u; } v; v.f = f;
    unsigned r = v.u + 0x7FFF + ((v.u >> 16) & 1);
    return (u16)(r >> 16);
}

// ---------------------------------------------------------------------------
// Wstack fragment builder (validated rounds 1-4).
// element (k,n) at: (k>>5)*16384 + (n>>4)*512 + ((k>>3)&3)*128 + (n&15)*8 + (k&7)
__global__ void k_wstack2(const float* __restrict__ basis, const float* __restrict__ comb,
                          const float* __restrict__ selfW, u16* __restrict__ wf) {
    int bi = blockIdx.x, t = threadIdx.x;
    int kr = t >> 7;             // 0..1
    int nb = (t & 127) * 4;      // n base
    for (int it = 0; it < 4; ++it) {
        int k = bi * 8 + it * 2 + kr;
        float v0, v1, v2, v3;
        if (k < 6144) {
            int r = k >> 9, h = k & 511;
            v0 = v1 = v2 = v3 = 0.f;
            for (int q = 0; q < 6; ++q) {
                float c = comb[r * 6 + q];
                const float4 bz = *(const float4*)(basis + ((size_t)(q * 512 + h)) * 512 + nb);
                v0 += c * bz.x; v1 += c * bz.y; v2 += c * bz.z; v3 += c * bz.w;
            }
        } else {
            int kk = k - 6144;
            v0 = selfW[(size_t)(nb + 0) * 512 + kk];
            v1 = selfW[(size_t)(nb + 1) * 512 + kk];
            v2 = selfW[(size_t)(nb + 2) * 512 + kk];
            v3 = selfW[(size_t)(nb + 3) * 512 + kk];
        }
        float vv[4] = {v0, v1, v2, v3};
        for (int i = 0; i < 4; ++i) {
            int n = nb + i;
            wf[(size_t)(k >> 5) * 16384 + (n >> 4) * 512 + ((k >> 3) & 3) * 128 + (n & 15) * 8 + (k & 7)] = f2bf(vv[i]);
        }
    }
}

// ---------------------------------------------------------------------------
// Adjacency prep (validated): adjA raw ch r+1; adjB updated+remapped.
__global__ void k_adj(const int* __restrict__ A, u16* __restrict__ adjA, u16* __restrict__ adjB) {
    int bi = blockIdx.x;          // b*12 + r
    int b = bi / 12, r = bi % 12;
    const int* Ab = A + (size_t)(b * 13 + (r + 1)) * 62 * 62;
    u16* oA = adjA + (size_t)bi * 64 * 64;
    u16* oB = adjB + (size_t)bi * 64 * 64;
    int t = threadIdx.x;
    int n = t >> 2, m0 = (t & 3) * 16;
    for (int i = 0; i < 16; ++i) {
        int m = m0 + i;
        u16 va = 0;
        if (n < 62 && m < 62) va = Ab[n * 62 + m] ? 0x3F80 : 0;
        oA[n * 64 + m] = va;
        u16 vb = 0;
        if (n < 63 && m < 63) {
            int oi = (n == 62) ? 63 : n, oj = (m == 62) ? 63 : m;
            int val = 0;
            if (oi < 62 && oj < 62) val = Ab[oi * 62 + oj] ? 1 : 0;
            int lo = (oi < oj) ? oi : oj, hi = (oi < oj) ? oj : oi;
            if (hi == lo + 2) {
                int p = (lo >> 1) & 1;
                int chp = ((lo & 1) == 0) ? (p ? 12 : 11) : (p ? 11 : 12);
                if (r + 1 == chp) val = 1;
            }
            vb = val ? 0x3F80 : 0;
        }
        oB[n * 64 + m] = vb;
    }
}

// ---------------------------------------------------------------------------
// initial embedding -> mi1 rows 60..63 ; mi2 rows 62,63
__global__ void k_prep(const int* __restrict__ player,
                       const float* __restrict__ pAx, const float* __restrict__ pAy,
                       const float* __restrict__ pBx, const float* __restrict__ pBy,
                       const float* __restrict__ emb, const float* __restrict__ cW,
                       const float* __restrict__ cb, const float* __restrict__ inW,
                       const float* __restrict__ inb,
                       u16* __restrict__ mi1, u16* __restrict__ mi2) {
    int b = blockIdx.x, t = threadIdx.x;
    __shared__ float feat[2][64];
    if (t < 64) {
        int j = t >> 5, d = t & 31;
        float X = j ? pBx[b] : pAx[b];
        float Y = j ? pBy[b] : pAy[b];
        feat[j][d] = fmaxf(cW[d * 2] * X + cW[d * 2 + 1] * Y + cb[d], 0.f);
        feat[j][32 + d] = emb[player[b * 2 + j] * 32 + d];
    }
    __syncthreads();
    for (int h = t; h < 512; h += 256) {
        float a0 = inb[h], a1 = inb[h];
        const float* wrow = inW + h * 64;
        #pragma unroll
        for (int d = 0; d < 64; ++d) {
            float wv = wrow[d];
            a0 += wv * feat[0][d];
            a1 += wv * feat[1][d];
        }
        u16 v0 = f2bf(a0), v1 = f2bf(a1);
        size_t base = (size_t)b * 64 * 512;
        mi1[base + 60 * 512 + h] = v0;
        mi1[base + 61 * 512 + h] = v1;
        mi1[base + 62 * 512 + h] = 0;
        mi1[base + 63 * 512 + h] = 0;
        mi2[base + 62 * 512 + h] = v1;
        mi2[base + 63 * 512 + h] = 0;
    }
}

// enc f32 -> mi1 rows 0..59 ; mi2 rows 0..57
__global__ void k_cast(const float* __restrict__ enc, u16* __restrict__ mi1, u16* __restrict__ mi2) {
    long long e = ((long long)blockIdx.x * 256 + threadIdx.x) * 8;
    if (e >= 256LL * 60 * 512) return;
    int b = (int)(e / (60 * 512));
    int rm = (int)(e % (60 * 512));
    int n = rm / 512, h = rm % 512;
    for (int i = 0; i < 8; ++i) {
        u16 v = f2bf(enc[e + i]);
        mi1[((size_t)b * 64 + n) * 512 + h + i] = v;
        if (n < 58) mi2[((size_t)b * 64 + n) * 512 + h + i] = v;
    }
}

// ---------------------------------------------------------------------------
// Fused RGCN layer, v2. Block = (batch b, 64-col tile ct in 0..7), 256 thr.
// XCD-pinned ct (blockIdx&7) so each XCD's L2 holds only its 851 KB W slice.
// K split in 2 halves (linearity); x held in registers; zs/adjs double-buffered
// -> one barrier per r; 36 KB LDS -> 4 blocks/CU.
__global__ __launch_bounds__(256, 4)
void k_fused(const u16* __restrict__ x, const u16* __restrict__ adj,
             const u16* __restrict__ wf, int mode,
             u16* __restrict__ o16, float* __restrict__ o32) {
    int ct = blockIdx.x & 7, b = blockIdx.x >> 3;
    int t = threadIdx.x, lane = t & 63, wm = t >> 6;  // 4 waves = 4 row bands
    int l15 = lane & 15, lq = lane >> 4;

    __shared__ __align__(16) u16 zs[2][64 * 72];    // Z^T: [col][m]
    __shared__ __align__(16) u16 adjs[2][64 * 72];  // adj_r[n][m]

    const u16* xb = x + (size_t)b * 64 * 512 + (wm * 16 + l15) * 512 + lq * 8;
    const u16* adjb = adj + (size_t)b * 12 * 4096;
    const u16* wbase = wf + (size_t)(ct * 4) * 512 + (size_t)lane * 8;

    floatx4 ay[4];
    #pragma unroll
    for (int i = 0; i < 4; ++i) ay[i] = (floatx4)(0.f);

    for (int kh = 0; kh < 2; ++kh) {
        short8 xf[8];
        #pragma unroll
        for (int ks = 0; ks < 8; ++ks)
            xf[ks] = *(const short8*)(xb + kh * 256 + ks * 32);

        for (int r = 0; r < 13; ++r) {
            int p = r & 1;
            if (r < 12) {
                int row = t >> 2, c8 = (t & 3) * 16;
                const u16* ap = adjb + r * 4096 + row * 64 + c8;
                *(short8*)&adjs[p][row * 72 + c8]     = *(const short8*)ap;
                *(short8*)&adjs[p][row * 72 + c8 + 8] = *(const short8*)(ap + 8);
            }
            // Z-phase: az = x_kh @ W[r,kh] (16 rows x 64 cols per wave)
            floatx4 az[4];
            #pragma unroll
            for (int i = 0; i < 4; ++i) az[i] = (floatx4)(0.f);
            const u16* wr = wbase + (size_t)(r * 16 + kh * 8) * 16384;
            short8 wv[4];
            #pragma unroll
            for (int i = 0; i < 4; ++i) wv[i] = *(const short8*)(wr + (size_t)i * 512);
            #pragma unroll
            for (int ks = 0; ks < 8; ++ks) {
                short8 wnx[4];
                if (ks < 7) {
                    const u16* wp = wr + (size_t)(ks + 1) * 16384;
                    #pragma unroll
                    for (int i = 0; i < 4; ++i) wnx[i] = *(const short8*)(wp + (size_t)i * 512);
                }
                #pragma unroll
                for (int i = 0; i < 4; ++i)
                    az[i] = __builtin_amdgcn_mfma_f32_16x16x32_bf16(xf[ks], wv[i], az[i], 0, 0, 0);
                if (ks < 7) {
                    #pragma unroll
                    for (int i = 0; i < 4; ++i) wv[i] = wnx[i];
                }
            }

            if (r < 12) {
                #pragma unroll
                for (int i = 0; i < 4; ++i) {
                    short4v pk;
                    #pragma unroll
                    for (int rr = 0; rr < 4; ++rr) pk[rr] = (short)f2bf(az[i][rr]);
                    *(short4v*)&zs[p][(i * 16 + l15) * 72 + wm * 16 + lq * 4] = pk;
                }
                __syncthreads();
                // agg: ay += adj_r @ Z_r
                #pragma unroll
                for (int k2 = 0; k2 < 2; ++k2) {
                    short8 af2 = *(const short8*)&adjs[p][(wm * 16 + l15) * 72 + k2 * 32 + lq * 8];
                    #pragma unroll
                    for (int i = 0; i < 4; ++i) {
                        short8 bf2 = *(const short8*)&zs[p][(i * 16 + l15) * 72 + k2 * 32 + lq * 8];
                        ay[i] = __builtin_amdgcn_mfma_f32_16x16x32_bf16(af2, bf2, ay[i], 0, 0, 0);
                    }
                }
            } else {
                #pragma unroll
                for (int i = 0; i < 4; ++i) ay[i] += az[i];
            }
        }
    }

    // epilogue
    #pragma unroll
    for (int i = 0; i < 4; ++i)
        #pragma unroll
        for (int rr = 0; rr < 4; ++rr) {
            int row = wm * 16 + lq * 4 + rr;
            int col = ct * 64 + i * 16 + l15;
            float v = ay[i][rr];
            if (mode == 0) {
                o16[((size_t)b * 64 + row) * 512 + col] = f2bf(fmaxf(v, 0.f));
            } else {
                float s = 1.f / (1.f + __expf(-v));
                if (mode == 1) {
                    if (row >= 58 && row <= 61)
                        o16[((size_t)b * 64 + row) * 512 + col] = f2bf(s);
                } else {
                    if (row == 60) o32[(size_t)(b * 2) * 512 + col] = s;
                    if (row == 62) o32[(size_t)(b * 2 + 1) * 512 + col] = s;
                }
            }
        }
}

// logits = [black|white] @ type_W^T + type_b
__global__ void k_final(const float* __restrict__ t2, const float* __restrict__ tW,
                        const float* __restrict__ tb, float* __restrict__ outp) {
    int b = blockIdx.x, l = threadIdx.x;   // 64 threads
    float a[11];
    #pragma unroll
    for (int j = 0; j < 11; ++j) a[j] = 0.f;
    for (int it = 0; it < 16; ++it) {
        int h = it * 64 + l;
        float c = (h < 512) ? t2[(b * 2 + 1) * 512 + h] : t2[(b * 2 + 0) * 512 + (h - 512)];
        #pragma unroll
        for (int j = 0; j < 11; ++j) a[j] += c * tW[j * 1024 + h];
    }
    #pragma unroll
    for (int j = 0; j < 11; ++j) {
        float v = a[j];
        for (int off = 32; off > 0; off >>= 1) v += __shfl_down(v, off, 64);
        if (l == 0) outp[b * 11 + j] = v + tb[j];
    }
}

// ---------------------------------------------------------------------------
extern "C" void kernel_launch(void* const* d_in, const int* in_sizes, int n_in,
                              void* d_out, int out_size, void* d_ws, size_t ws_size,
                              hipStream_t stream) {
    const int*   player = (const int*)d_in[0];
    const float* enc    = (const float*)d_in[2];
    const int*   adjm   = (const int*)d_in[3];
    const float* pAx    = (const float*)d_in[4];
    const float* pAy    = (const float*)d_in[5];
    const float* pBx    = (const float*)d_in[6];
    const float* pBy    = (const float*)d_in[7];
    const float* emb    = (const float*)d_in[8];
    const float* cW     = (const float*)d_in[9];
    const float* cb     = (const float*)d_in[10];
    const float* inW    = (const float*)d_in[11];
    const float* inb    = (const float*)d_in[12];
    const float* basis0 = (const float*)d_in[13];
    const float* comb0  = (const float*)d_in[14];
    const float* self0  = (const float*)d_in[15];
    const float* basis1 = (const float*)d_in[16];
    const float* comb1  = (const float*)d_in[17];
    const float* self1  = (const float*)d_in[18];
    const float* typeW  = (const float*)d_in[19];
    const float* typeb  = (const float*)d_in[20];

    char* ws = (char*)d_ws;
    size_t off = 0;
    auto alloc = [&](size_t bytes) -> void* {
        void* p = ws + off;
        off = (off + bytes + 255) & ~(size_t)255;
        return p;
    };
    u16* mi1  = (u16*)alloc(256UL * 64 * 512 * 2);
    u16* mi2  = (u16*)alloc(256UL * 64 * 512 * 2);
    u16* x12  = (u16*)alloc(256UL * 64 * 512 * 2);
    u16* x12b = (u16*)alloc(256UL * 64 * 512 * 2);
    u16* adjA = (u16*)alloc(256UL * 12 * 64 * 64 * 2);
    u16* adjB = (u16*)alloc(256UL * 12 * 64 * 64 * 2);
    u16* wf0  = (u16*)alloc(208UL * 32 * 64 * 8 * 2);
    u16* wf1  = (u16*)alloc(208UL * 32 * 64 * 8 * 2);
    float* t2 = (float*)alloc(512UL * 512 * 4);

    k_wstack2<<<832, 256, 0, stream>>>(basis0, comb0, self0, wf0);
    k_wstack2<<<832, 256, 0, stream>>>(basis1, comb1, self1, wf1);
    k_adj<<<3072, 256, 0, stream>>>(adjm, adjA, adjB);
    k_prep<<<256, 256, 0, stream>>>(player, pAx, pAy, pBx, pBy, emb, cW, cb, inW, inb, mi1, mi2);
    k_cast<<<3840, 256, 0, stream>>>(enc, mi1, mi2);

    // rgcn pass 1
    k_fused<<<2048, 256, 0, stream>>>(mi1, adjA, wf0, 0, x12, nullptr);
    k_fused<<<2048, 256, 0, stream>>>(x12, adjA, wf1, 1, mi2, nullptr);
    // rgcn pass 2
    k_fused<<<2048, 256, 0, stream>>>(mi2, adjB, wf0, 0, x12b, nullptr);
    k_fused<<<2048, 256, 0, stream>>>(x12b, adjB, wf1, 2, nullptr, t2);

    k_final<<<256, 64, 0, stream>>>(t2, typeW, typeb, (float*)d_out);
}

// Round 6
// 1111.645 us; speedup vs baseline: 2.2721x; 1.2155x over previous
//
#include <hip/hip_runtime.h>
#include <hip/hip_bf16.h>

typedef unsigned short u16;
typedef unsigned long long u64;
typedef __attribute__((ext_vector_type(4))) short short4v;
typedef __attribute__((ext_vector_type(8))) short short8;
typedef __attribute__((ext_vector_type(4))) float floatx4;

__device__ __forceinline__ u16 f2bf(float f) {
    union { float f; unsigned u; } v; v.f = f;
    unsigned r = v.u + 0x7FFF + ((v.u >> 16) & 1);
    return (u16)(r >> 16);
}

// ---------------------------------------------------------------------------
// Wstack fragment builder (validated rounds 1-5).
// element (k,n) at: (k>>5)*16384 + (n>>4)*512 + ((k>>3)&3)*128 + (n&15)*8 + (k&7)
__global__ void k_wstack2(const float* __restrict__ basis, const float* __restrict__ comb,
                          const float* __restrict__ selfW, u16* __restrict__ wf) {
    int bi = blockIdx.x, t = threadIdx.x;
    int kr = t >> 7;             // 0..1
    int nb = (t & 127) * 4;      // n base
    for (int it = 0; it < 4; ++it) {
        int k = bi * 8 + it * 2 + kr;
        float v0, v1, v2, v3;
        if (k < 6144) {
            int r = k >> 9, h = k & 511;
            v0 = v1 = v2 = v3 = 0.f;
            for (int q = 0; q < 6; ++q) {
                float c = comb[r * 6 + q];
                const float4 bz = *(const float4*)(basis + ((size_t)(q * 512 + h)) * 512 + nb);
                v0 += c * bz.x; v1 += c * bz.y; v2 += c * bz.z; v3 += c * bz.w;
            }
        } else {
            int kk = k - 6144;
            v0 = selfW[(size_t)(nb + 0) * 512 + kk];
            v1 = selfW[(size_t)(nb + 1) * 512 + kk];
            v2 = selfW[(size_t)(nb + 2) * 512 + kk];
            v3 = selfW[(size_t)(nb + 3) * 512 + kk];
        }
        float vv[4] = {v0, v1, v2, v3};
        for (int i = 0; i < 4; ++i) {
            int n = nb + i;
            wf[(size_t)(k >> 5) * 16384 + (n >> 4) * 512 + ((k >> 3) & 3) * 128 + (n & 15) * 8 + (k & 7)] = f2bf(vv[i]);
        }
    }
}

// ---------------------------------------------------------------------------
// Bit-packed adjacency: bA/bB[b][12][64] u64 masks (bit m of word n = adj[n][m]).
// Same remap/parity logic as the validated bf16 k_adj.
__global__ void k_adjbits(const int* __restrict__ A, u64* __restrict__ bA, u64* __restrict__ bB) {
    int bi = blockIdx.x;          // b*12 + r
    int b = bi / 12, r = bi % 12;
    const int* Ab = A + (size_t)(b * 13 + (r + 1)) * 62 * 62;
    __shared__ int tile[62 * 62];
    for (int i = threadIdx.x; i < 3844; i += 256) tile[i] = Ab[i];
    __syncthreads();
    int n = threadIdx.x;
    if (n < 64) {
        u64 mA = 0, mB = 0;
        if (n < 62)
            for (int m = 0; m < 62; ++m)
                if (tile[n * 62 + m]) mA |= 1ull << m;
        if (n < 63) {
            int oi = (n == 62) ? 63 : n;
            for (int m = 0; m < 63; ++m) {
                int oj = (m == 62) ? 63 : m;
                int val = (oi < 62 && oj < 62) ? (tile[oi * 62 + oj] ? 1 : 0) : 0;
                int lo = (oi < oj) ? oi : oj, hi = (oi < oj) ? oj : oi;
                if (hi == lo + 2) {
                    int p = (lo >> 1) & 1;
                    int chp = ((lo & 1) == 0) ? (p ? 12 : 11) : (p ? 11 : 12);
                    if (r + 1 == chp) val = 1;
                }
                if (val) mB |= 1ull << m;
            }
        }
        bA[(size_t)bi * 64 + n] = mA;
        bB[(size_t)bi * 64 + n] = mB;
    }
}

// ---------------------------------------------------------------------------
// initial embedding -> mi1 rows 60..63 ; mi2 rows 62,63
__global__ void k_prep(const int* __restrict__ player,
                       const float* __restrict__ pAx, const float* __restrict__ pAy,
                       const float* __restrict__ pBx, const float* __restrict__ pBy,
                       const float* __restrict__ emb, const float* __restrict__ cW,
                       const float* __restrict__ cb, const float* __restrict__ inW,
                       const float* __restrict__ inb,
                       u16* __restrict__ mi1, u16* __restrict__ mi2) {
    int b = blockIdx.x, t = threadIdx.x;
    __shared__ float feat[2][64];
    if (t < 64) {
        int j = t >> 5, d = t & 31;
        float X = j ? pBx[b] : pAx[b];
        float Y = j ? pBy[b] : pAy[b];
        feat[j][d] = fmaxf(cW[d * 2] * X + cW[d * 2 + 1] * Y + cb[d], 0.f);
        feat[j][32 + d] = emb[player[b * 2 + j] * 32 + d];
    }
    __syncthreads();
    for (int h = t; h < 512; h += 256) {
        float a0 = inb[h], a1 = inb[h];
        const float* wrow = inW + h * 64;
        #pragma unroll
        for (int d = 0; d < 64; ++d) {
            float wv = wrow[d];
            a0 += wv * feat[0][d];
            a1 += wv * feat[1][d];
        }
        u16 v0 = f2bf(a0), v1 = f2bf(a1);
        size_t base = (size_t)b * 64 * 512;
        mi1[base + 60 * 512 + h] = v0;
        mi1[base + 61 * 512 + h] = v1;
        mi1[base + 62 * 512 + h] = 0;
        mi1[base + 63 * 512 + h] = 0;
        mi2[base + 62 * 512 + h] = v1;
        mi2[base + 63 * 512 + h] = 0;
    }
}

// enc f32 -> mi1 rows 0..59 ; mi2 rows 0..57
__global__ void k_cast(const float* __restrict__ enc, u16* __restrict__ mi1, u16* __restrict__ mi2) {
    long long e = ((long long)blockIdx.x * 256 + threadIdx.x) * 8;
    if (e >= 256LL * 60 * 512) return;
    int b = (int)(e / (60 * 512));
    int rm = (int)(e % (60 * 512));
    int n = rm / 512, h = rm % 512;
    for (int i = 0; i < 8; ++i) {
        u16 v = f2bf(enc[e + i]);
        mi1[((size_t)b * 64 + n) * 512 + h + i] = v;
        if (n < 58) mi2[((size_t)b * 64 + n) * 512 + h + i] = v;
    }
}

// ---------------------------------------------------------------------------
// Fused RGCN layer, v3. Block = (2 batches, 64-col tile ct), 512 thr = 8 waves.
// Wave (g, kq): batch g, K-quarter kq. Z-partials -> zs (K=256 concat);
// aggregation y = adjrep @ [Zp0;Zp1;Zp2;Zp3] (+ identity for self term).
// adj from bit-packed masks expanded in LDS. XCD-pinned ct (blockIdx&7).
__global__ __launch_bounds__(512, 2)
void k_fused(const u16* __restrict__ x, const u64* __restrict__ bits,
             const u16* __restrict__ wf, int mode,
             u16* __restrict__ o16, float* __restrict__ o32) {
    int ct = blockIdx.x & 7, bg = blockIdx.x >> 3;
    int b0 = bg * 2;
    int t = threadIdx.x, lane = t & 63, w = t >> 6;
    int g = w & 1, kq = w >> 1;
    int l15 = lane & 15, lq = lane >> 4;

    __shared__ __align__(16) u16 zs[2][64 * 264];    // [g][col][m' 0..255]
    __shared__ __align__(16) u16 adjs[2][64 * 72];   // [g][n][m]

    // x fragments: batch g, all 64 rows, K-quarter kq (16 frags, one-time load)
    short8 xf[16];
    {
        const u16* xw = x + (size_t)(b0 + g) * 64 * 512 + kq * 128 + lq * 8;
        #pragma unroll
        for (int mt = 0; mt < 4; ++mt)
            #pragma unroll
            for (int ks = 0; ks < 4; ++ks)
                xf[mt * 4 + ks] = *(const short8*)(xw + (mt * 16 + l15) * 512 + ks * 32);
    }
    // identity A-fragments for the self term (A[n][m'] = 1 iff m'%64 == n)
    short8 idf[2];
    #pragma unroll
    for (int h = 0; h < 2; ++h)
        #pragma unroll
        for (int j = 0; j < 8; ++j)
            idf[h][j] = (short)((kq * 16 + l15 == h * 32 + lq * 8 + j) ? 0x3F80 : 0);

    const u16* wbase = wf + (size_t)(ct * 4) * 512 + (size_t)lane * 8;
    const u64* bit0 = bits + (size_t)b0 * 12 * 64;

    floatx4 ay[4];
    #pragma unroll
    for (int i = 0; i < 4; ++i) ay[i] = (floatx4)(0.f);

    for (int r = 0; r < 13; ++r) {
        // ---- Z-phase: az = x_q @ W[r, quarter kq] (64 rows x 64 cols partial)
        const u16* wr = wbase + (size_t)(r * 16 + kq * 4) * 16384;
        floatx4 az[16];
        #pragma unroll
        for (int i = 0; i < 16; ++i) az[i] = (floatx4)(0.f);
        short8 wv[4];
        #pragma unroll
        for (int i = 0; i < 4; ++i) wv[i] = *(const short8*)(wr + (size_t)i * 512);
        #pragma unroll
        for (int ks = 0; ks < 4; ++ks) {
            short8 wn_[4];
            if (ks < 3) {
                const u16* wp = wr + (size_t)(ks + 1) * 16384;
                #pragma unroll
                for (int i = 0; i < 4; ++i) wn_[i] = *(const short8*)(wp + (size_t)i * 512);
            }
            #pragma unroll
            for (int mt = 0; mt < 4; ++mt)
                #pragma unroll
                for (int i = 0; i < 4; ++i)
                    az[mt * 4 + i] = __builtin_amdgcn_mfma_f32_16x16x32_bf16(xf[mt * 4 + ks], wv[i], az[mt * 4 + i], 0, 0, 0);
            if (ks < 3) {
                #pragma unroll
                for (int i = 0; i < 4; ++i) wv[i] = wn_[i];
            }
        }

        __syncthreads();   // previous agg's zs/adjs reads complete

        // ---- write Z-partials: zs[g][col][kq*64 + row]
        #pragma unroll
        for (int mt = 0; mt < 4; ++mt)
            #pragma unroll
            for (int i = 0; i < 4; ++i) {
                short4v pk;
                #pragma unroll
                for (int rr = 0; rr < 4; ++rr) pk[rr] = (short)f2bf(az[mt * 4 + i][rr]);
                *(short4v*)&zs[g][(i * 16 + l15) * 264 + kq * 64 + mt * 16 + lq * 4] = pk;
            }
        // ---- stage adj_r for both batches from bitmasks
        if (r < 12) {
            int gg = t >> 8, n = (t >> 2) & 63, m0 = (t & 3) * 16;
            u64 mk = bit0[(size_t)(gg * 12 + r) * 64 + n] >> m0;
            short8 v0, v1;
            #pragma unroll
            for (int j = 0; j < 8; ++j) {
                v0[j] = (short)(((mk >> j) & 1) ? 0x3F80 : 0);
                v1[j] = (short)(((mk >> (j + 8)) & 1) ? 0x3F80 : 0);
            }
            *(short8*)&adjs[gg][n * 72 + m0]     = v0;
            *(short8*)&adjs[gg][n * 72 + m0 + 8] = v1;
        }
        __syncthreads();   // zs + adjs ready

        // ---- aggregation: ay += adjrep @ [Zp0;Zp1;Zp2;Zp3]  (K=256)
        short8 afa, afb;
        if (r < 12) {
            afa = *(const short8*)&adjs[g][(kq * 16 + l15) * 72 + lq * 8];
            afb = *(const short8*)&adjs[g][(kq * 16 + l15) * 72 + 32 + lq * 8];
        } else {
            afa = idf[0]; afb = idf[1];
        }
        #pragma unroll
        for (int k2 = 0; k2 < 8; ++k2) {
            short8 af2 = (k2 & 1) ? afb : afa;
            #pragma unroll
            for (int i = 0; i < 4; ++i) {
                short8 bz = *(const short8*)&zs[g][(i * 16 + l15) * 264 + k2 * 32 + lq * 8];
                ay[i] = __builtin_amdgcn_mfma_f32_16x16x32_bf16(af2, bz, ay[i], 0, 0, 0);
            }
        }
    }

    // ---- epilogue: wave (g,kq) owns rows kq*16..+16 of batch b0+g
    int b = b0 + g;
    #pragma unroll
    for (int i = 0; i < 4; ++i)
        #pragma unroll
        for (int rr = 0; rr < 4; ++rr) {
            int row = kq * 16 + lq * 4 + rr;
            int col = ct * 64 + i * 16 + l15;
            float v = ay[i][rr];
            if (mode == 0) {
                o16[((size_t)b * 64 + row) * 512 + col] = f2bf(fmaxf(v, 0.f));
            } else {
                float s = 1.f / (1.f + __expf(-v));
                if (mode == 1) {
                    if (row >= 58 && row <= 61)
                        o16[((size_t)b * 64 + row) * 512 + col] = f2bf(s);
                } else {
                    if (row == 60) o32[(size_t)(b * 2) * 512 + col] = s;
                    if (row == 62) o32[(size_t)(b * 2 + 1) * 512 + col] = s;
                }
            }
        }
}

// logits = [black|white] @ type_W^T + type_b
__global__ void k_final(const float* __restrict__ t2, const float* __restrict__ tW,
                        const float* __restrict__ tb, float* __restrict__ outp) {
    int b = blockIdx.x, l = threadIdx.x;   // 64 threads
    float a[11];
    #pragma unroll
    for (int j = 0; j < 11; ++j) a[j] = 0.f;
    for (int it = 0; it < 16; ++it) {
        int h = it * 64 + l;
        float c = (h < 512) ? t2[(b * 2 + 1) * 512 + h] : t2[(b * 2 + 0) * 512 + (h - 512)];
        #pragma unroll
        for (int j = 0; j < 11; ++j) a[j] += c * tW[j * 1024 + h];
    }
    #pragma unroll
    for (int j = 0; j < 11; ++j) {
        float v = a[j];
        for (int off = 32; off > 0; off >>= 1) v += __shfl_down(v, off, 64);
        if (l == 0) outp[b * 11 + j] = v + tb[j];
    }
}

// ---------------------------------------------------------------------------
extern "C" void kernel_launch(void* const* d_in, const int* in_sizes, int n_in,
                              void* d_out, int out_size, void* d_ws, size_t ws_size,
                              hipStream_t stream) {
    const int*   player = (const int*)d_in[0];
    const float* enc    = (const float*)d_in[2];
    const int*   adjm   = (const int*)d_in[3];
    const float* pAx    = (const float*)d_in[4];
    const float* pAy    = (const float*)d_in[5];
    const float* pBx    = (const float*)d_in[6];
    const float* pBy    = (const float*)d_in[7];
    const float* emb    = (const float*)d_in[8];
    const float* cW     = (const float*)d_in[9];
    const float* cb     = (const float*)d_in[10];
    const float* inW    = (const float*)d_in[11];
    const float* inb    = (const float*)d_in[12];
    const float* basis0 = (const float*)d_in[13];
    const float* comb0  = (const float*)d_in[14];
    const float* self0  = (const float*)d_in[15];
    const float* basis1 = (const float*)d_in[16];
    const float* comb1  = (const float*)d_in[17];
    const float* self1  = (const float*)d_in[18];
    const float* typeW  = (const float*)d_in[19];
    const float* typeb  = (const float*)d_in[20];

    char* ws = (char*)d_ws;
    size_t off = 0;
    auto alloc = [&](size_t bytes) -> void* {
        void* p = ws + off;
        off = (off + bytes + 255) & ~(size_t)255;
        return p;
    };
    u16* mi1   = (u16*)alloc(256UL * 64 * 512 * 2);
    u16* mi2   = (u16*)alloc(256UL * 64 * 512 * 2);
    u16* x12   = (u16*)alloc(256UL * 64 * 512 * 2);
    u16* x12b  = (u16*)alloc(256UL * 64 * 512 * 2);
    u64* bitsA = (u64*)alloc(256UL * 12 * 64 * 8);
    u64* bitsB = (u64*)alloc(256UL * 12 * 64 * 8);
    u16* wf0   = (u16*)alloc(208UL * 32 * 64 * 8 * 2);
    u16* wf1   = (u16*)alloc(208UL * 32 * 64 * 8 * 2);
    float* t2  = (float*)alloc(512UL * 512 * 4);

    k_wstack2<<<832, 256, 0, stream>>>(basis0, comb0, self0, wf0);
    k_wstack2<<<832, 256, 0, stream>>>(basis1, comb1, self1, wf1);
    k_adjbits<<<3072, 256, 0, stream>>>(adjm, bitsA, bitsB);
    k_prep<<<256, 256, 0, stream>>>(player, pAx, pAy, pBx, pBy, emb, cW, cb, inW, inb, mi1, mi2);
    k_cast<<<3840, 256, 0, stream>>>(enc, mi1, mi2);

    // rgcn pass 1
    k_fused<<<1024, 512, 0, stream>>>(mi1, bitsA, wf0, 0, x12, nullptr);
    k_fused<<<1024, 512, 0, stream>>>(x12, bitsA, wf1, 1, mi2, nullptr);
    // rgcn pass 2
    k_fused<<<1024, 512, 0, stream>>>(mi2, bitsB, wf0, 0, x12b, nullptr);
    k_fused<<<1024, 512, 0, stream>>>(x12b, bitsB, wf1, 2, nullptr, t2);

    k_final<<<256, 64, 0, stream>>>(t2, typeW, typeb, (float*)d_out);
}

// Round 7
// 972.386 us; speedup vs baseline: 2.5975x; 1.1432x over previous
//
#include <hip/hip_runtime.h>
#include <hip/hip_bf16.h>

typedef unsigned short u16;
typedef unsigned long long u64;
typedef __attribute__((ext_vector_type(4))) short short4v;
typedef __attribute__((ext_vector_type(8))) short short8;
typedef __attribute__((ext_vector_type(4))) float floatx4;

__device__ __forceinline__ u16 f2bf(float f) {
    union { float f; unsigned u; } v; v.f = f;
    unsigned r = v.u + 0x7FFF + ((v.u >> 16) & 1);
    return (u16)(r >> 16);
}

// ---------------------------------------------------------------------------
// Wstack fragment builder (validated rounds 1-6).
// element (k,n) at: (k>>5)*16384 + (n>>4)*512 + ((k>>3)&3)*128 + (n&15)*8 + (k&7)
__global__ void k_wstack2(const float* __restrict__ basis, const float* __restrict__ comb,
                          const float* __restrict__ selfW, u16* __restrict__ wf) {
    int bi = blockIdx.x, t = threadIdx.x;
    int kr = t >> 7;             // 0..1
    int nb = (t & 127) * 4;      // n base
    for (int it = 0; it < 4; ++it) {
        int k = bi * 8 + it * 2 + kr;
        float v0, v1, v2, v3;
        if (k < 6144) {
            int r = k >> 9, h = k & 511;
            v0 = v1 = v2 = v3 = 0.f;
            for (int q = 0; q < 6; ++q) {
                float c = comb[r * 6 + q];
                const float4 bz = *(const float4*)(basis + ((size_t)(q * 512 + h)) * 512 + nb);
                v0 += c * bz.x; v1 += c * bz.y; v2 += c * bz.z; v3 += c * bz.w;
            }
        } else {
            int kk = k - 6144;
            v0 = selfW[(size_t)(nb + 0) * 512 + kk];
            v1 = selfW[(size_t)(nb + 1) * 512 + kk];
            v2 = selfW[(size_t)(nb + 2) * 512 + kk];
            v3 = selfW[(size_t)(nb + 3) * 512 + kk];
        }
        float vv[4] = {v0, v1, v2, v3};
        for (int i = 0; i < 4; ++i) {
            int n = nb + i;
            wf[(size_t)(k >> 5) * 16384 + (n >> 4) * 512 + ((k >> 3) & 3) * 128 + (n & 15) * 8 + (k & 7)] = f2bf(vv[i]);
        }
    }
}

// ---------------------------------------------------------------------------
// Bit-packed adjacency (validated round 6): bA/bB[b][12][64] u64 masks.
__global__ void k_adjbits(const int* __restrict__ A, u64* __restrict__ bA, u64* __restrict__ bB) {
    int bi = blockIdx.x;          // b*12 + r
    int b = bi / 12, r = bi % 12;
    const int* Ab = A + (size_t)(b * 13 + (r + 1)) * 62 * 62;
    __shared__ int tile[62 * 62];
    for (int i = threadIdx.x; i < 3844; i += 256) tile[i] = Ab[i];
    __syncthreads();
    int n = threadIdx.x;
    if (n < 64) {
        u64 mA = 0, mB = 0;
        if (n < 62)
            for (int m = 0; m < 62; ++m)
                if (tile[n * 62 + m]) mA |= 1ull << m;
        if (n < 63) {
            int oi = (n == 62) ? 63 : n;
            for (int m = 0; m < 63; ++m) {
                int oj = (m == 62) ? 63 : m;
                int val = (oi < 62 && oj < 62) ? (tile[oi * 62 + oj] ? 1 : 0) : 0;
                int lo = (oi < oj) ? oi : oj, hi = (oi < oj) ? oj : oi;
                if (hi == lo + 2) {
                    int p = (lo >> 1) & 1;
                    int chp = ((lo & 1) == 0) ? (p ? 12 : 11) : (p ? 11 : 12);
                    if (r + 1 == chp) val = 1;
                }
                if (val) mB |= 1ull << m;
            }
        }
        bA[(size_t)bi * 64 + n] = mA;
        bB[(size_t)bi * 64 + n] = mB;
    }
}

// ---------------------------------------------------------------------------
// initial embedding -> mi1 rows 60..63 ; mi2 rows 62,63
__global__ void k_prep(const int* __restrict__ player,
                       const float* __restrict__ pAx, const float* __restrict__ pAy,
                       const float* __restrict__ pBx, const float* __restrict__ pBy,
                       const float* __restrict__ emb, const float* __restrict__ cW,
                       const float* __restrict__ cb, const float* __restrict__ inW,
                       const float* __restrict__ inb,
                       u16* __restrict__ mi1, u16* __restrict__ mi2) {
    int b = blockIdx.x, t = threadIdx.x;
    __shared__ float feat[2][64];
    if (t < 64) {
        int j = t >> 5, d = t & 31;
        float X = j ? pBx[b] : pAx[b];
        float Y = j ? pBy[b] : pAy[b];
        feat[j][d] = fmaxf(cW[d * 2] * X + cW[d * 2 + 1] * Y + cb[d], 0.f);
        feat[j][32 + d] = emb[player[b * 2 + j] * 32 + d];
    }
    __syncthreads();
    for (int h = t; h < 512; h += 256) {
        float a0 = inb[h], a1 = inb[h];
        const float* wrow = inW + h * 64;
        #pragma unroll
        for (int d = 0; d < 64; ++d) {
            float wv = wrow[d];
            a0 += wv * feat[0][d];
            a1 += wv * feat[1][d];
        }
        u16 v0 = f2bf(a0), v1 = f2bf(a1);
        size_t base = (size_t)b * 64 * 512;
        mi1[base + 60 * 512 + h] = v0;
        mi1[base + 61 * 512 + h] = v1;
        mi1[base + 62 * 512 + h] = 0;
        mi1[base + 63 * 512 + h] = 0;
        mi2[base + 62 * 512 + h] = v1;
        mi2[base + 63 * 512 + h] = 0;
    }
}

// enc f32 -> mi1 rows 0..59 ; mi2 rows 0..57
__global__ void k_cast(const float* __restrict__ enc, u16* __restrict__ mi1, u16* __restrict__ mi2) {
    long long e = ((long long)blockIdx.x * 256 + threadIdx.x) * 8;
    if (e >= 256LL * 60 * 512) return;
    int b = (int)(e / (60 * 512));
    int rm = (int)(e % (60 * 512));
    int n = rm / 512, h = rm % 512;
    for (int i = 0; i < 8; ++i) {
        u16 v = f2bf(enc[e + i]);
        mi1[((size_t)b * 64 + n) * 512 + h + i] = v;
        if (n < 58) mi2[((size_t)b * 64 + n) * 512 + h + i] = v;
    }
}

// ---------------------------------------------------------------------------
// Fused RGCN layer, v4. Block = (1 batch, 64-col tile ct), 256 thr = 4 waves.
// Wave w: Z-phase K-quarter w; agg-phase col-band w.
// Z partials -> zs [col][m'=w*64+row]; agg computes y^T = Z^T @ adj^T with
// A from zs (own col-band only) and B expanded from bit-masks in registers.
// 33.8 KB LDS, ~2 waves/SIMD -> 2 independent blocks/CU (phase overlap).
__global__ __launch_bounds__(256, 2)
void k_fused(const u16* __restrict__ x, const u64* __restrict__ bits,
             const u16* __restrict__ wf, int mode,
             u16* __restrict__ o16, float* __restrict__ o32) {
    int ct = blockIdx.x & 7, b = blockIdx.x >> 3;
    int t = threadIdx.x, lane = t & 63, w = t >> 6;
    int l15 = lane & 15, lq = lane >> 4;

    __shared__ __align__(16) u16 zs[64 * 264];   // [col][m' 0..255]

    // x fragments: all 64 rows, K-quarter w (one-time load)
    short8 xf[16];
    {
        const u16* xw = x + (size_t)b * 64 * 512 + w * 128 + lq * 8;
        #pragma unroll
        for (int mt = 0; mt < 4; ++mt)
            #pragma unroll
            for (int ks = 0; ks < 4; ++ks)
                xf[mt * 4 + ks] = *(const short8*)(xw + (mt * 16 + l15) * 512 + ks * 32);
    }

    const u16* wbase = wf + (size_t)(ct * 4) * 512 + (size_t)lane * 8;
    const u64* bitb = bits + (size_t)b * 12 * 64;

    floatx4 ay[4];
    #pragma unroll
    for (int i = 0; i < 4; ++i) ay[i] = (floatx4)(0.f);

    for (int r = 0; r < 13; ++r) {
        // adj masks for agg B-operand: mk[i] = mask[row = i*16+l15]
        u64 mk[4];
        if (r < 12) {
            #pragma unroll
            for (int i = 0; i < 4; ++i) mk[i] = bitb[r * 64 + i * 16 + l15];
        } else {
            #pragma unroll
            for (int i = 0; i < 4; ++i) mk[i] = 1ull << (i * 16 + l15);  // self: identity
        }

        // ---- Z-phase: az = x_q @ W[r, quarter w]  (64 rows x 64 cols partial)
        const u16* wr = wbase + (size_t)(r * 16 + w * 4) * 16384;
        floatx4 az[16];
        #pragma unroll
        for (int i = 0; i < 16; ++i) az[i] = (floatx4)(0.f);
        short8 wv[4];
        #pragma unroll
        for (int i = 0; i < 4; ++i) wv[i] = *(const short8*)(wr + (size_t)i * 512);
        #pragma unroll
        for (int ks = 0; ks < 4; ++ks) {
            short8 wn_[4];
            if (ks < 3) {
                const u16* wp = wr + (size_t)(ks + 1) * 16384;
                #pragma unroll
                for (int i = 0; i < 4; ++i) wn_[i] = *(const short8*)(wp + (size_t)i * 512);
            }
            #pragma unroll
            for (int mt = 0; mt < 4; ++mt)
                #pragma unroll
                for (int i = 0; i < 4; ++i)
                    az[mt * 4 + i] = __builtin_amdgcn_mfma_f32_16x16x32_bf16(xf[mt * 4 + ks], wv[i], az[mt * 4 + i], 0, 0, 0);
            if (ks < 3) {
                #pragma unroll
                for (int i = 0; i < 4; ++i) wv[i] = wn_[i];
            }
        }

        __syncthreads();   // prior agg's zs reads complete

        // ---- write Z-partials: zs[col][w*64 + row]
        #pragma unroll
        for (int mt = 0; mt < 4; ++mt)
            #pragma unroll
            for (int i = 0; i < 4; ++i) {
                short4v pk;
                #pragma unroll
                for (int rr = 0; rr < 4; ++rr) pk[rr] = (short)f2bf(az[mt * 4 + i][rr]);
                *(short4v*)&zs[(i * 16 + l15) * 264 + w * 64 + mt * 16 + lq * 4] = pk;
            }

        // expand adj B-fragments (depends only on k2 parity and i)
        short8 adjf[8];   // [i*2+par]
        #pragma unroll
        for (int i = 0; i < 4; ++i)
            #pragma unroll
            for (int par = 0; par < 2; ++par) {
                unsigned byte = (unsigned)((mk[i] >> (par * 32 + lq * 8)) & 0xFFu);
                #pragma unroll
                for (int j = 0; j < 8; ++j)
                    adjf[i * 2 + par][j] = (short)(((byte >> j) & 1) ? 0x3F80 : 0);
            }

        __syncthreads();   // zs visible

        // ---- agg: ay^T += Z^T @ adj^T  (A = zs own col-band, B = adjf)
        #pragma unroll
        for (int k2 = 0; k2 < 8; ++k2) {
            short8 af = *(const short8*)&zs[(w * 16 + l15) * 264 + k2 * 32 + lq * 8];
            #pragma unroll
            for (int i = 0; i < 4; ++i)
                ay[i] = __builtin_amdgcn_mfma_f32_16x16x32_bf16(af, adjf[i * 2 + (k2 & 1)], ay[i], 0, 0, 0);
        }
    }

    // ---- epilogue: lane holds y[row = i*16+l15][col = ct*64 + w*16 + lq*4 + rr]
    int colb = ct * 64 + w * 16 + lq * 4;
    #pragma unroll
    for (int i = 0; i < 4; ++i) {
        int row = i * 16 + l15;
        if (mode == 0) {
            short4v pk;
            #pragma unroll
            for (int rr = 0; rr < 4; ++rr) pk[rr] = (short)f2bf(fmaxf(ay[i][rr], 0.f));
            *(short4v*)(o16 + ((size_t)b * 64 + row) * 512 + colb) = pk;
        } else if (mode == 1) {
            if (row >= 58 && row <= 61) {
                short4v pk;
                #pragma unroll
                for (int rr = 0; rr < 4; ++rr)
                    pk[rr] = (short)f2bf(1.f / (1.f + __expf(-ay[i][rr])));
                *(short4v*)(o16 + ((size_t)b * 64 + row) * 512 + colb) = pk;
            }
        } else {
            if (row == 60 || row == 62) {
                float4 pv;
                pv.x = 1.f / (1.f + __expf(-ay[i][0]));
                pv.y = 1.f / (1.f + __expf(-ay[i][1]));
                pv.z = 1.f / (1.f + __expf(-ay[i][2]));
                pv.w = 1.f / (1.f + __expf(-ay[i][3]));
                int slot = (row == 60) ? (b * 2) : (b * 2 + 1);
                *(float4*)(o32 + (size_t)slot * 512 + colb) = pv;
            }
        }
    }
}

// logits = [black|white] @ type_W^T + type_b
__global__ void k_final(const float* __restrict__ t2, const float* __restrict__ tW,
                        const float* __restrict__ tb, float* __restrict__ outp) {
    int b = blockIdx.x, l = threadIdx.x;   // 64 threads
    float a[11];
    #pragma unroll
    for (int j = 0; j < 11; ++j) a[j] = 0.f;
    for (int it = 0; it < 16; ++it) {
        int h = it * 64 + l;
        float c = (h < 512) ? t2[(b * 2 + 1) * 512 + h] : t2[(b * 2 + 0) * 512 + (h - 512)];
        #pragma unroll
        for (int j = 0; j < 11; ++j) a[j] += c * tW[j * 1024 + h];
    }
    #pragma unroll
    for (int j = 0; j < 11; ++j) {
        float v = a[j];
        for (int off = 32; off > 0; off >>= 1) v += __shfl_down(v, off, 64);
        if (l == 0) outp[b * 11 + j] = v + tb[j];
    }
}

// ---------------------------------------------------------------------------
extern "C" void kernel_launch(void* const* d_in, const int* in_sizes, int n_in,
                              void* d_out, int out_size, void* d_ws, size_t ws_size,
                              hipStream_t stream) {
    const int*   player = (const int*)d_in[0];
    const float* enc    = (const float*)d_in[2];
    const int*   adjm   = (const int*)d_in[3];
    const float* pAx    = (const float*)d_in[4];
    const float* pAy    = (const float*)d_in[5];
    const float* pBx    = (const float*)d_in[6];
    const float* pBy    = (const float*)d_in[7];
    const float* emb    = (const float*)d_in[8];
    const float* cW     = (const float*)d_in[9];
    const float* cb     = (const float*)d_in[10];
    const float* inW    = (const float*)d_in[11];
    const float* inb    = (const float*)d_in[12];
    const float* basis0 = (const float*)d_in[13];
    const float* comb0  = (const float*)d_in[14];
    const float* self0  = (const float*)d_in[15];
    const float* basis1 = (const float*)d_in[16];
    const float* comb1  = (const float*)d_in[17];
    const float* self1  = (const float*)d_in[18];
    const float* typeW  = (const float*)d_in[19];
    const float* typeb  = (const float*)d_in[20];

    char* ws = (char*)d_ws;
    size_t off = 0;
    auto alloc = [&](size_t bytes) -> void* {
        void* p = ws + off;
        off = (off + bytes + 255) & ~(size_t)255;
        return p;
    };
    u16* mi1   = (u16*)alloc(256UL * 64 * 512 * 2);
    u16* mi2   = (u16*)alloc(256UL * 64 * 512 * 2);
    u16* x12   = (u16*)alloc(256UL * 64 * 512 * 2);
    u16* x12b  = (u16*)alloc(256UL * 64 * 512 * 2);
    u64* bitsA = (u64*)alloc(256UL * 12 * 64 * 8);
    u64* bitsB = (u64*)alloc(256UL * 12 * 64 * 8);
    u16* wf0   = (u16*)alloc(208UL * 32 * 64 * 8 * 2);
    u16* wf1   = (u16*)alloc(208UL * 32 * 64 * 8 * 2);
    float* t2  = (float*)alloc(512UL * 512 * 4);

    k_wstack2<<<832, 256, 0, stream>>>(basis0, comb0, self0, wf0);
    k_wstack2<<<832, 256, 0, stream>>>(basis1, comb1, self1, wf1);
    k_adjbits<<<3072, 256, 0, stream>>>(adjm, bitsA, bitsB);
    k_prep<<<256, 256, 0, stream>>>(player, pAx, pAy, pBx, pBy, emb, cW, cb, inW, inb, mi1, mi2);
    k_cast<<<3840, 256, 0, stream>>>(enc, mi1, mi2);

    // rgcn pass 1
    k_fused<<<2048, 256, 0, stream>>>(mi1, bitsA, wf0, 0, x12, nullptr);
    k_fused<<<2048, 256, 0, stream>>>(x12, bitsA, wf1, 1, mi2, nullptr);
    // rgcn pass 2
    k_fused<<<2048, 256, 0, stream>>>(mi2, bitsB, wf0, 0, x12b, nullptr);
    k_fused<<<2048, 256, 0, stream>>>(x12b, bitsB, wf1, 2, nullptr, t2);

    k_final<<<256, 64, 0, stream>>>(t2, typeW, typeb, (float*)d_out);
}

// Round 8
// 952.658 us; speedup vs baseline: 2.6512x; 1.0207x over previous
//
#include <hip/hip_runtime.h>
#include <hip/hip_bf16.h>

typedef unsigned short u16;
typedef unsigned long long u64;
typedef __attribute__((ext_vector_type(4))) short short4v;
typedef __attribute__((ext_vector_type(8))) short short8;
typedef __attribute__((ext_vector_type(4))) float floatx4;

__device__ __forceinline__ u16 f2bf(float f) {
    union { float f; unsigned u; } v; v.f = f;
    unsigned r = v.u + 0x7FFF + ((v.u >> 16) & 1);
    return (u16)(r >> 16);
}

// packed f32x2 -> bf16x2 (low = a). HW v_cvt_pk_bf16_f32 on gfx950.
__device__ __forceinline__ unsigned pk2bf(float a, float b) {
#if defined(__has_builtin)
#if __has_builtin(__builtin_amdgcn_cvt_pk_bf16_f32)
    auto v = __builtin_amdgcn_cvt_pk_bf16_f32(a, b);
    unsigned u; __builtin_memcpy(&u, &v, 4); return u;
#else
    return (unsigned)f2bf(a) | ((unsigned)f2bf(b) << 16);
#endif
#else
    return (unsigned)f2bf(a) | ((unsigned)f2bf(b) << 16);
#endif
}

// ---------------------------------------------------------------------------
// Wstack fragment builder (validated rounds 1-7).
// element (k,n) at: (k>>5)*16384 + (n>>4)*512 + ((k>>3)&3)*128 + (n&15)*8 + (k&7)
__global__ void k_wstack2(const float* __restrict__ basis, const float* __restrict__ comb,
                          const float* __restrict__ selfW, u16* __restrict__ wf) {
    int bi = blockIdx.x, t = threadIdx.x;
    int kr = t >> 7;             // 0..1
    int nb = (t & 127) * 4;      // n base
    for (int it = 0; it < 4; ++it) {
        int k = bi * 8 + it * 2 + kr;
        float v0, v1, v2, v3;
        if (k < 6144) {
            int r = k >> 9, h = k & 511;
            v0 = v1 = v2 = v3 = 0.f;
            for (int q = 0; q < 6; ++q) {
                float c = comb[r * 6 + q];
                const float4 bz = *(const float4*)(basis + ((size_t)(q * 512 + h)) * 512 + nb);
                v0 += c * bz.x; v1 += c * bz.y; v2 += c * bz.z; v3 += c * bz.w;
            }
        } else {
            int kk = k - 6144;
            v0 = selfW[(size_t)(nb + 0) * 512 + kk];
            v1 = selfW[(size_t)(nb + 1) * 512 + kk];
            v2 = selfW[(size_t)(nb + 2) * 512 + kk];
            v3 = selfW[(size_t)(nb + 3) * 512 + kk];
        }
        float vv[4] = {v0, v1, v2, v3};
        for (int i = 0; i < 4; ++i) {
            int n = nb + i;
            wf[(size_t)(k >> 5) * 16384 + (n >> 4) * 512 + ((k >> 3) & 3) * 128 + (n & 15) * 8 + (k & 7)] = f2bf(vv[i]);
        }
    }
}

// ---------------------------------------------------------------------------
// Bit-packed adjacency (validated round 6): bA/bB[b][12][64] u64 masks.
__global__ void k_adjbits(const int* __restrict__ A, u64* __restrict__ bA, u64* __restrict__ bB) {
    int bi = blockIdx.x;          // b*12 + r
    int b = bi / 12, r = bi % 12;
    const int* Ab = A + (size_t)(b * 13 + (r + 1)) * 62 * 62;
    __shared__ int tile[62 * 62];
    for (int i = threadIdx.x; i < 3844; i += 256) tile[i] = Ab[i];
    __syncthreads();
    int n = threadIdx.x;
    if (n < 64) {
        u64 mA = 0, mB = 0;
        if (n < 62)
            for (int m = 0; m < 62; ++m)
                if (tile[n * 62 + m]) mA |= 1ull << m;
        if (n < 63) {
            int oi = (n == 62) ? 63 : n;
            for (int m = 0; m < 63; ++m) {
                int oj = (m == 62) ? 63 : m;
                int val = (oi < 62 && oj < 62) ? (tile[oi * 62 + oj] ? 1 : 0) : 0;
                int lo = (oi < oj) ? oi : oj, hi = (oi < oj) ? oj : oi;
                if (hi == lo + 2) {
                    int p = (lo >> 1) & 1;
                    int chp = ((lo & 1) == 0) ? (p ? 12 : 11) : (p ? 11 : 12);
                    if (r + 1 == chp) val = 1;
                }
                if (val) mB |= 1ull << m;
            }
        }
        bA[(size_t)bi * 64 + n] = mA;
        bB[(size_t)bi * 64 + n] = mB;
    }
}

// ---------------------------------------------------------------------------
// initial embedding -> mi1 rows 60..63 ; mi2 rows 62,63
__global__ void k_prep(const int* __restrict__ player,
                       const float* __restrict__ pAx, const float* __restrict__ pAy,
                       const float* __restrict__ pBx, const float* __restrict__ pBy,
                       const float* __restrict__ emb, const float* __restrict__ cW,
                       const float* __restrict__ cb, const float* __restrict__ inW,
                       const float* __restrict__ inb,
                       u16* __restrict__ mi1, u16* __restrict__ mi2) {
    int b = blockIdx.x, t = threadIdx.x;
    __shared__ float feat[2][64];
    if (t < 64) {
        int j = t >> 5, d = t & 31;
        float X = j ? pBx[b] : pAx[b];
        float Y = j ? pBy[b] : pAy[b];
        feat[j][d] = fmaxf(cW[d * 2] * X + cW[d * 2 + 1] * Y + cb[d], 0.f);
        feat[j][32 + d] = emb[player[b * 2 + j] * 32 + d];
    }
    __syncthreads();
    for (int h = t; h < 512; h += 256) {
        float a0 = inb[h], a1 = inb[h];
        const float* wrow = inW + h * 64;
        #pragma unroll
        for (int d = 0; d < 64; ++d) {
            float wv = wrow[d];
            a0 += wv * feat[0][d];
            a1 += wv * feat[1][d];
        }
        u16 v0 = f2bf(a0), v1 = f2bf(a1);
        size_t base = (size_t)b * 64 * 512;
        mi1[base + 60 * 512 + h] = v0;
        mi1[base + 61 * 512 + h] = v1;
        mi1[base + 62 * 512 + h] = 0;
        mi1[base + 63 * 512 + h] = 0;
        mi2[base + 62 * 512 + h] = v1;
        mi2[base + 63 * 512 + h] = 0;
    }
}

// enc f32 -> mi1 rows 0..59 ; mi2 rows 0..57
__global__ void k_cast(const float* __restrict__ enc, u16* __restrict__ mi1, u16* __restrict__ mi2) {
    long long e = ((long long)blockIdx.x * 256 + threadIdx.x) * 8;
    if (e >= 256LL * 60 * 512) return;
    int b = (int)(e / (60 * 512));
    int rm = (int)(e % (60 * 512));
    int n = rm / 512, h = rm % 512;
    for (int i = 0; i < 8; ++i) {
        u16 v = f2bf(enc[e + i]);
        mi1[((size_t)b * 64 + n) * 512 + h + i] = v;
        if (n < 58) mi2[((size_t)b * 64 + n) * 512 + h + i] = v;
    }
}

// ---------------------------------------------------------------------------
// Fused RGCN layer, v5. Block = (1 batch, 64-col tile ct), 256 thr = 4 waves.
// Wave w: Z-phase K-quarter w; agg-phase col-band w.
// v5: packed v_cvt_pk_bf16_f32 for all f32->bf16; mode 1/2 skip agg row-tiles
// 0..2 (outputs live in row tile i=3 only).
__global__ __launch_bounds__(256, 2)
void k_fused(const u16* __restrict__ x, const u64* __restrict__ bits,
             const u16* __restrict__ wf, int mode,
             u16* __restrict__ o16, float* __restrict__ o32) {
    int ct = blockIdx.x & 7, b = blockIdx.x >> 3;
    int t = threadIdx.x, lane = t & 63, w = t >> 6;
    int l15 = lane & 15, lq = lane >> 4;

    __shared__ __align__(16) u16 zs[64 * 264];   // [col][m' 0..255]

    // x fragments: all 64 rows, K-quarter w (one-time load)
    short8 xf[16];
    {
        const u16* xw = x + (size_t)b * 64 * 512 + w * 128 + lq * 8;
        #pragma unroll
        for (int mt = 0; mt < 4; ++mt)
            #pragma unroll
            for (int ks = 0; ks < 4; ++ks)
                xf[mt * 4 + ks] = *(const short8*)(xw + (mt * 16 + l15) * 512 + ks * 32);
    }

    const u16* wbase = wf + (size_t)(ct * 4) * 512 + (size_t)lane * 8;
    const u64* bitb = bits + (size_t)b * 12 * 64;

    floatx4 ay[4];
    #pragma unroll
    for (int i = 0; i < 4; ++i) ay[i] = (floatx4)(0.f);

    for (int r = 0; r < 13; ++r) {
        // adj masks (row = i*16+l15); self term = identity
        u64 mk[4];
        if (mode == 0) {
            if (r < 12) {
                #pragma unroll
                for (int i = 0; i < 4; ++i) mk[i] = bitb[r * 64 + i * 16 + l15];
            } else {
                #pragma unroll
                for (int i = 0; i < 4; ++i) mk[i] = 1ull << (i * 16 + l15);
            }
        } else {
            mk[3] = (r < 12) ? bitb[r * 64 + 48 + l15] : (1ull << (48 + l15));
        }

        // ---- Z-phase: az = x_q @ W[r, quarter w]  (64 rows x 64 cols partial)
        const u16* wr = wbase + (size_t)(r * 16 + w * 4) * 16384;
        floatx4 az[16];
        #pragma unroll
        for (int i = 0; i < 16; ++i) az[i] = (floatx4)(0.f);
        short8 wv[4];
        #pragma unroll
        for (int i = 0; i < 4; ++i) wv[i] = *(const short8*)(wr + (size_t)i * 512);
        #pragma unroll
        for (int ks = 0; ks < 4; ++ks) {
            short8 wn_[4];
            if (ks < 3) {
                const u16* wp = wr + (size_t)(ks + 1) * 16384;
                #pragma unroll
                for (int i = 0; i < 4; ++i) wn_[i] = *(const short8*)(wp + (size_t)i * 512);
            }
            #pragma unroll
            for (int mt = 0; mt < 4; ++mt)
                #pragma unroll
                for (int i = 0; i < 4; ++i)
                    az[mt * 4 + i] = __builtin_amdgcn_mfma_f32_16x16x32_bf16(xf[mt * 4 + ks], wv[i], az[mt * 4 + i], 0, 0, 0);
            if (ks < 3) {
                #pragma unroll
                for (int i = 0; i < 4; ++i) wv[i] = wn_[i];
            }
        }

        __syncthreads();   // prior agg's zs reads complete

        // ---- write Z-partials (packed cvt): zs[col][w*64 + row]
        #pragma unroll
        for (int mt = 0; mt < 4; ++mt)
            #pragma unroll
            for (int i = 0; i < 4; ++i) {
                uint2 pk;
                pk.x = pk2bf(az[mt * 4 + i][0], az[mt * 4 + i][1]);
                pk.y = pk2bf(az[mt * 4 + i][2], az[mt * 4 + i][3]);
                *(uint2*)&zs[(i * 16 + l15) * 264 + w * 64 + mt * 16 + lq * 4] = pk;
            }

        __syncthreads();   // zs visible

        // ---- agg: ay^T += Z^T @ adj^T  (A = zs own col-band, B from bitmasks)
        if (mode == 0) {
            short8 adjf[8];   // [i*2+par]
            #pragma unroll
            for (int i = 0; i < 4; ++i)
                #pragma unroll
                for (int par = 0; par < 2; ++par) {
                    unsigned byte = (unsigned)((mk[i] >> (par * 32 + lq * 8)) & 0xFFu);
                    #pragma unroll
                    for (int j = 0; j < 8; ++j)
                        adjf[i * 2 + par][j] = (short)(((byte >> j) & 1) ? 0x3F80 : 0);
                }
            #pragma unroll
            for (int k2 = 0; k2 < 8; ++k2) {
                short8 af = *(const short8*)&zs[(w * 16 + l15) * 264 + k2 * 32 + lq * 8];
                #pragma unroll
                for (int i = 0; i < 4; ++i)
                    ay[i] = __builtin_amdgcn_mfma_f32_16x16x32_bf16(af, adjf[i * 2 + (k2 & 1)], ay[i], 0, 0, 0);
            }
        } else {
            short8 adjf[2];
            #pragma unroll
            for (int par = 0; par < 2; ++par) {
                unsigned byte = (unsigned)((mk[3] >> (par * 32 + lq * 8)) & 0xFFu);
                #pragma unroll
                for (int j = 0; j < 8; ++j)
                    adjf[par][j] = (short)(((byte >> j) & 1) ? 0x3F80 : 0);
            }
            #pragma unroll
            for (int k2 = 0; k2 < 8; ++k2) {
                short8 af = *(const short8*)&zs[(w * 16 + l15) * 264 + k2 * 32 + lq * 8];
                ay[3] = __builtin_amdgcn_mfma_f32_16x16x32_bf16(af, adjf[k2 & 1], ay[3], 0, 0, 0);
            }
        }
    }

    // ---- epilogue: lane holds y[row = i*16+l15][col = ct*64 + w*16 + lq*4 + rr]
    int colb = ct * 64 + w * 16 + lq * 4;
    #pragma unroll
    for (int i = 0; i < 4; ++i) {
        int row = i * 16 + l15;
        if (mode == 0) {
            uint2 pk;
            pk.x = pk2bf(fmaxf(ay[i][0], 0.f), fmaxf(ay[i][1], 0.f));
            pk.y = pk2bf(fmaxf(ay[i][2], 0.f), fmaxf(ay[i][3], 0.f));
            *(uint2*)(o16 + ((size_t)b * 64 + row) * 512 + colb) = pk;
        } else if (mode == 1) {
            if (i == 3 && row >= 58 && row <= 61) {
                uint2 pk;
                pk.x = pk2bf(1.f / (1.f + __expf(-ay[3][0])), 1.f / (1.f + __expf(-ay[3][1])));
                pk.y = pk2bf(1.f / (1.f + __expf(-ay[3][2])), 1.f / (1.f + __expf(-ay[3][3])));
                *(uint2*)(o16 + ((size_t)b * 64 + row) * 512 + colb) = pk;
            }
        } else {
            if (i == 3 && (row == 60 || row == 62)) {
                float4 pv;
                pv.x = 1.f / (1.f + __expf(-ay[3][0]));
                pv.y = 1.f / (1.f + __expf(-ay[3][1]));
                pv.z = 1.f / (1.f + __expf(-ay[3][2]));
                pv.w = 1.f / (1.f + __expf(-ay[3][3]));
                int slot = (row == 60) ? (b * 2) : (b * 2 + 1);
                *(float4*)(o32 + (size_t)slot * 512 + colb) = pv;
            }
        }
    }
}

// logits = [black|white] @ type_W^T + type_b
__global__ void k_final(const float* __restrict__ t2, const float* __restrict__ tW,
                        const float* __restrict__ tb, float* __restrict__ outp) {
    int b = blockIdx.x, l = threadIdx.x;   // 64 threads
    float a[11];
    #pragma unroll
    for (int j = 0; j < 11; ++j) a[j] = 0.f;
    for (int it = 0; it < 16; ++it) {
        int h = it * 64 + l;
        float c = (h < 512) ? t2[(b * 2 + 1) * 512 + h] : t2[(b * 2 + 0) * 512 + (h - 512)];
        #pragma unroll
        for (int j = 0; j < 11; ++j) a[j] += c * tW[j * 1024 + h];
    }
    #pragma unroll
    for (int j = 0; j < 11; ++j) {
        float v = a[j];
        for (int off = 32; off > 0; off >>= 1) v += __shfl_down(v, off, 64);
        if (l == 0) outp[b * 11 + j] = v + tb[j];
    }
}

// ---------------------------------------------------------------------------
extern "C" void kernel_launch(void* const* d_in, const int* in_sizes, int n_in,
                              void* d_out, int out_size, void* d_ws, size_t ws_size,
                              hipStream_t stream) {
    const int*   player = (const int*)d_in[0];
    const float* enc    = (const float*)d_in[2];
    const int*   adjm   = (const int*)d_in[3];
    const float* pAx    = (const float*)d_in[4];
    const float* pAy    = (const float*)d_in[5];
    const float* pBx    = (const float*)d_in[6];
    const float* pBy    = (const float*)d_in[7];
    const float* emb    = (const float*)d_in[8];
    const float* cW     = (const float*)d_in[9];
    const float* cb     = (const float*)d_in[10];
    const float* inW    = (const float*)d_in[11];
    const float* inb    = (const float*)d_in[12];
    const float* basis0 = (const float*)d_in[13];
    const float* comb0  = (const float*)d_in[14];
    const float* self0  = (const float*)d_in[15];
    const float* basis1 = (const float*)d_in[16];
    const float* comb1  = (const float*)d_in[17];
    const float* self1  = (const float*)d_in[18];
    const float* typeW  = (const float*)d_in[19];
    const float* typeb  = (const float*)d_in[20];

    char* ws = (char*)d_ws;
    size_t off = 0;
    auto alloc = [&](size_t bytes) -> void* {
        void* p = ws + off;
        off = (off + bytes + 255) & ~(size_t)255;
        return p;
    };
    u16* mi1   = (u16*)alloc(256UL * 64 * 512 * 2);
    u16* mi2   = (u16*)alloc(256UL * 64 * 512 * 2);
    u16* x12   = (u16*)alloc(256UL * 64 * 512 * 2);
    u16* x12b  = (u16*)alloc(256UL * 64 * 512 * 2);
    u64* bitsA = (u64*)alloc(256UL * 12 * 64 * 8);
    u64* bitsB = (u64*)alloc(256UL * 12 * 64 * 8);
    u16* wf0   = (u16*)alloc(208UL * 32 * 64 * 8 * 2);
    u16* wf1   = (u16*)alloc(208UL * 32 * 64 * 8 * 2);
    float* t2  = (float*)alloc(512UL * 512 * 4);

    k_wstack2<<<832, 256, 0, stream>>>(basis0, comb0, self0, wf0);
    k_wstack2<<<832, 256, 0, stream>>>(basis1, comb1, self1, wf1);
    k_adjbits<<<3072, 256, 0, stream>>>(adjm, bitsA, bitsB);
    k_prep<<<256, 256, 0, stream>>>(player, pAx, pAy, pBx, pBy, emb, cW, cb, inW, inb, mi1, mi2);
    k_cast<<<3840, 256, 0, stream>>>(enc, mi1, mi2);

    // rgcn pass 1
    k_fused<<<2048, 256, 0, stream>>>(mi1, bitsA, wf0, 0, x12, nullptr);
    k_fused<<<2048, 256, 0, stream>>>(x12, bitsA, wf1, 1, mi2, nullptr);
    // rgcn pass 2
    k_fused<<<2048, 256, 0, stream>>>(mi2, bitsB, wf0, 0, x12b, nullptr);
    k_fused<<<2048, 256, 0, stream>>>(x12b, bitsB, wf1, 2, nullptr, t2);

    k_final<<<256, 64, 0, stream>>>(t2, typeW, typeb, (float*)d_out);
}